// Round 1
// baseline (810.071 us; speedup 1.0000x reference)
//
#include <hip/hip_runtime.h>
#include <stdint.h>

#define NPIX 4096

typedef __bf16 bf16x8 __attribute__((ext_vector_type(8)));
typedef float  f32x4  __attribute__((ext_vector_type(4)));

union FragU {
  bf16x8 f;
  uint4  u;
  unsigned short s[8];
};

static __device__ __forceinline__ unsigned short f2bf(float x) {
  unsigned int u = __float_as_uint(x);
  u += 0x7FFFu + ((u >> 16) & 1u);
  return (unsigned short)(u >> 16);
}

static __device__ __forceinline__ unsigned int pack2(unsigned short a, unsigned short b) {
  return (unsigned int)a | ((unsigned int)b << 16);
}

// Loads one 8-bf16 MFMA fragment (16x16x32 layout: elems 0..3 at byteOff,
// elems 4..7 at byteOff+32, where byteOff already includes (lane>>4)*8).
static __device__ __forceinline__ bf16x8 load_frag(const unsigned short* base, int byteOff) {
  const char* p = reinterpret_cast<const char*>(base) + byteOff;
  uint2 a = *reinterpret_cast<const uint2*>(p);
  uint2 b = *reinterpret_cast<const uint2*>(p + 32);
  FragU fu;
  fu.u = make_uint4(a.x, a.y, b.x, b.y);
  return fu.f;
}

// ---------------------------------------------------------------------------
// Kernel 1: q,k,v = 1x1 conv.  qT,kT stored (B,N,64) bf16; v stored (B,64,N).
// grid (16, 8, 4): x = pixel tile (256 px), y = batch, z = o-chunk of 16.
// ---------------------------------------------------------------------------
__global__ __launch_bounds__(256) void qkv_proj(
    const float* __restrict__ x,
    const float* __restrict__ Wq, const float* __restrict__ bq,
    const float* __restrict__ Wk, const float* __restrict__ bk,
    const float* __restrict__ Wv, const float* __restrict__ bv,
    unsigned short* __restrict__ qT, unsigned short* __restrict__ kT,
    unsigned short* __restrict__ vC)
{
  const int t  = threadIdx.x;
  const int b  = blockIdx.y;
  const int n  = blockIdx.x * 256 + t;
  const int o0 = blockIdx.z * 16;

  float xv[64];
  #pragma unroll
  for (int c = 0; c < 64; ++c) xv[c] = x[((size_t)b * 64 + c) * NPIX + n];

  const float* Wp[3] = {Wq, Wk, Wv};
  const float* Bp[3] = {bq, bk, bv};

  #pragma unroll
  for (int p = 0; p < 3; ++p) {
    const float* W  = Wp[p];
    const float* Bv = Bp[p];
    unsigned short outv[16];
    #pragma unroll
    for (int oo = 0; oo < 16; ++oo) {
      float acc = Bv[o0 + oo];
      #pragma unroll
      for (int c = 0; c < 64; ++c) acc += W[(o0 + oo) * 64 + c] * xv[c];
      outv[oo] = f2bf(acc);
    }
    if (p < 2) {
      unsigned short* dst = (p == 0 ? qT : kT) + ((size_t)b * NPIX + n) * 64 + o0;
      uint4 w0 = make_uint4(pack2(outv[0], outv[1]),  pack2(outv[2], outv[3]),
                            pack2(outv[4], outv[5]),  pack2(outv[6], outv[7]));
      uint4 w1 = make_uint4(pack2(outv[8], outv[9]),  pack2(outv[10], outv[11]),
                            pack2(outv[12], outv[13]), pack2(outv[14], outv[15]));
      *reinterpret_cast<uint4*>(dst)     = w0;
      *reinterpret_cast<uint4*>(dst + 8) = w1;
    } else {
      #pragma unroll
      for (int oo = 0; oo < 16; ++oo)
        vC[((size_t)b * 64 + o0 + oo) * NPIX + n] = outv[oo];
    }
  }
}

// ---------------------------------------------------------------------------
// Kernel 2: rcpZ[b,j] = 1 / sum_i exp(q_j . k_i).
// grid (64, 8): x = j-block of 64 (each wave: 16 j rows), y = batch.
// ---------------------------------------------------------------------------
__global__ __launch_bounds__(256) void attn_rowsum(
    const unsigned short* __restrict__ qT, const unsigned short* __restrict__ kT,
    float* __restrict__ rcpZ)
{
  const int t    = threadIdx.x;
  const int b    = blockIdx.y;
  const int lane = t & 63;
  const int wv   = t >> 6;
  const int j0   = blockIdx.x * 64 + wv * 16;
  const int lr   = lane & 15;
  const int lg   = lane >> 4;

  const unsigned short* qrow = qT + ((size_t)b * NPIX + j0 + lr) * 64;
  const bf16x8 aq0 = load_frag(qrow, lg * 8);
  const bf16x8 aq1 = load_frag(qrow, 64 + lg * 8);

  float zs0 = 0.f, zs1 = 0.f, zs2 = 0.f, zs3 = 0.f;
  const unsigned short* kbase = kT + (size_t)b * NPIX * 64;

  for (int i0 = 0; i0 < NPIX; i0 += 16) {
    const unsigned short* krow = kbase + (size_t)(i0 + lr) * 64;
    bf16x8 bk0 = load_frag(krow, lg * 8);
    bf16x8 bk1 = load_frag(krow, 64 + lg * 8);
    f32x4 acc = {0.f, 0.f, 0.f, 0.f};
    acc = __builtin_amdgcn_mfma_f32_16x16x32_bf16(aq0, bk0, acc, 0, 0, 0);
    acc = __builtin_amdgcn_mfma_f32_16x16x32_bf16(aq1, bk1, acc, 0, 0, 0);
    zs0 += __expf(acc[0]);
    zs1 += __expf(acc[1]);
    zs2 += __expf(acc[2]);
    zs3 += __expf(acc[3]);
  }
  // reduce over the 16 lanes (lr) sharing the same lg group
  #pragma unroll
  for (int m = 8; m >= 1; m >>= 1) {
    zs0 += __shfl_xor(zs0, m, 64);
    zs1 += __shfl_xor(zs1, m, 64);
    zs2 += __shfl_xor(zs2, m, 64);
    zs3 += __shfl_xor(zs3, m, 64);
  }
  if (lr == 0) {
    const size_t base = (size_t)b * NPIX + j0 + lg * 4;
    rcpZ[base + 0] = 1.0f / zs0;
    rcpZ[base + 1] = 1.0f / zs1;
    rcpZ[base + 2] = 1.0f / zs2;
    rcpZ[base + 3] = 1.0f / zs3;
  }
}

// ---------------------------------------------------------------------------
// Kernel 3: res[b,c,i] = sum_j exp(q_j.k_i)*rcpZ_j * v[c,j].
// grid (64, 8): x = i-block of 64 (each wave: 16 i cols), y = batch.
// S-tile MFMA output (rows=j, cols=i) chains directly into the PV MFMA
// B-operand (contraction over j).
// ---------------------------------------------------------------------------
__global__ __launch_bounds__(256) void attn_pv(
    const unsigned short* __restrict__ qT, const unsigned short* __restrict__ kT,
    const unsigned short* __restrict__ vC, const float* __restrict__ rcpZ,
    float* __restrict__ res)
{
  __shared__ float sR[NPIX];
  const int t = threadIdx.x;
  const int b = blockIdx.y;
  for (int idx = t; idx < NPIX; idx += 256)
    sR[idx] = rcpZ[(size_t)b * NPIX + idx];
  __syncthreads();

  const int lane = t & 63;
  const int wv   = t >> 6;
  const int i0   = blockIdx.x * 64 + wv * 16;
  const int lr   = lane & 15;
  const int lg   = lane >> 4;

  const unsigned short* krow = kT + ((size_t)b * NPIX + i0 + lr) * 64;
  const bf16x8 bk0 = load_frag(krow, lg * 8);
  const bf16x8 bk1 = load_frag(krow, 64 + lg * 8);

  f32x4 acc[4];
  #pragma unroll
  for (int m = 0; m < 4; ++m) acc[m] = (f32x4){0.f, 0.f, 0.f, 0.f};

  const unsigned short* qbase = qT + (size_t)b * NPIX * 64;
  const unsigned short* vbase = vC + (size_t)b * 64 * NPIX;

  for (int j0 = 0; j0 < NPIX; j0 += 32) {
    const unsigned short* q0 = qbase + (size_t)(j0 + lr) * 64;
    const unsigned short* q1 = q0 + 16 * 64;
    f32x4 s0 = {0.f, 0.f, 0.f, 0.f}, s1 = {0.f, 0.f, 0.f, 0.f};
    s0 = __builtin_amdgcn_mfma_f32_16x16x32_bf16(load_frag(q0, lg * 8),      bk0, s0, 0, 0, 0);
    s0 = __builtin_amdgcn_mfma_f32_16x16x32_bf16(load_frag(q0, 64 + lg * 8), bk1, s0, 0, 0, 0);
    s1 = __builtin_amdgcn_mfma_f32_16x16x32_bf16(load_frag(q1, lg * 8),      bk0, s1, 0, 0, 0);
    s1 = __builtin_amdgcn_mfma_f32_16x16x32_bf16(load_frag(q1, 64 + lg * 8), bk1, s1, 0, 0, 0);

    FragU pe;
    #pragma unroll
    for (int r = 0; r < 4; ++r) {
      pe.s[r]     = f2bf(__expf(s0[r]) * sR[j0 + lg * 4 + r]);
      pe.s[4 + r] = f2bf(__expf(s1[r]) * sR[j0 + 16 + lg * 4 + r]);
    }

    #pragma unroll
    for (int m = 0; m < 4; ++m) {
      const unsigned short* vrow = vbase + (size_t)(m * 16 + lr) * NPIX + j0;
      bf16x8 av = load_frag(vrow, lg * 8);
      acc[m] = __builtin_amdgcn_mfma_f32_16x16x32_bf16(av, pe.f, acc[m], 0, 0, 0);
    }
  }

  #pragma unroll
  for (int m = 0; m < 4; ++m) {
    #pragma unroll
    for (int r = 0; r < 4; ++r) {
      res[((size_t)b * 64 + m * 16 + lg * 4 + r) * NPIX + i0 + lr] = acc[m][r];
    }
  }
}

// ---------------------------------------------------------------------------
// Kernel 4: out = Wo*res + bo + res.   grid (16, 8, 4) like qkv_proj.
// ---------------------------------------------------------------------------
__global__ __launch_bounds__(256) void out_proj(
    const float* __restrict__ res, const float* __restrict__ Wo,
    const float* __restrict__ bo, float* __restrict__ out)
{
  const int t  = threadIdx.x;
  const int b  = blockIdx.y;
  const int n  = blockIdx.x * 256 + t;
  const int o0 = blockIdx.z * 16;

  float rv[64];
  #pragma unroll
  for (int c = 0; c < 64; ++c) rv[c] = res[((size_t)b * 64 + c) * NPIX + n];

  #pragma unroll
  for (int oo = 0; oo < 16; ++oo) {
    float acc = bo[o0 + oo];
    #pragma unroll
    for (int c = 0; c < 64; ++c) acc += Wo[(o0 + oo) * 64 + c] * rv[c];
    // residual: reload (o0 is runtime -> avoid dynamic reg indexing of rv)
    acc += res[((size_t)b * 64 + o0 + oo) * NPIX + n];
    out[((size_t)b * 64 + o0 + oo) * NPIX + n] = acc;
  }
}

// ---------------------------------------------------------------------------
extern "C" void kernel_launch(void* const* d_in, const int* in_sizes, int n_in,
                              void* d_out, int out_size, void* d_ws, size_t ws_size,
                              hipStream_t stream) {
  const float* x  = (const float*)d_in[0];
  const float* Wq = (const float*)d_in[1];
  const float* bq = (const float*)d_in[2];
  const float* Wk = (const float*)d_in[3];
  const float* bk = (const float*)d_in[4];
  const float* Wv = (const float*)d_in[5];
  const float* bv = (const float*)d_in[6];
  const float* Wo = (const float*)d_in[7];
  const float* bo = (const float*)d_in[8];
  float* out = (float*)d_out;

  char* ws = (char*)d_ws;
  unsigned short* qT = (unsigned short*)(ws);                         // 4 MB
  unsigned short* kT = (unsigned short*)(ws + ((size_t)4 << 20));     // 4 MB
  unsigned short* vC = (unsigned short*)(ws + ((size_t)8 << 20));     // 4 MB
  float* rcpZ        = (float*)(ws + ((size_t)12 << 20));             // 128 KB
  float* res         = (float*)(ws + ((size_t)12 << 20) + (1 << 17)); // 8 MB

  qkv_proj<<<dim3(16, 8, 4), 256, 0, stream>>>(x, Wq, bq, Wk, bk, Wv, bv, qT, kT, vC);
  attn_rowsum<<<dim3(64, 8), 256, 0, stream>>>(qT, kT, rcpZ);
  attn_pv<<<dim3(64, 8), 256, 0, stream>>>(qT, kT, vC, rcpZ, res);
  out_proj<<<dim3(16, 8, 4), 256, 0, stream>>>(res, Wo, bo, out);
}

// Round 2
// 277.135 us; speedup vs baseline: 2.9230x; 2.9230x over previous
//
#include <hip/hip_runtime.h>
#include <stdint.h>

#define NPIX 4096

typedef __bf16 bf16x8 __attribute__((ext_vector_type(8)));
typedef float  f32x4  __attribute__((ext_vector_type(4)));
typedef unsigned long long ull;

union FragU {
  bf16x8 f;
  uint4  u;
  ull    q[2];
  unsigned short s[8];
};

static __device__ __forceinline__ unsigned short f2bf(float x) {
  unsigned int u = __float_as_uint(x);
  u += 0x7FFFu + ((u >> 16) & 1u);
  return (unsigned short)(u >> 16);
}

static __device__ __forceinline__ float bf2f(unsigned short s) {
  return __uint_as_float(((unsigned int)s) << 16);
}

static __device__ __forceinline__ unsigned int pack2(unsigned short a, unsigned short b) {
  return (unsigned int)a | ((unsigned int)b << 16);
}

// Global-memory fragment load (16x16x32 A/B layout: 8B at byteOff, 8B at +32).
static __device__ __forceinline__ bf16x8 load_frag(const unsigned short* base, int byteOff) {
  const char* p = reinterpret_cast<const char*>(base) + byteOff;
  uint2 a = *reinterpret_cast<const uint2*>(p);
  uint2 b = *reinterpret_cast<const uint2*>(p + 32);
  FragU fu;
  fu.u = make_uint4(a.x, a.y, b.x, b.y);
  return fu.f;
}

// LDS fragment load from a 64x64-short tile stored row-major with
// byte-swizzle L = P ^ ((row&7)<<4).  cb in [0,128), includes lg*8 (+ks*64).
static __device__ __forceinline__ bf16x8 lds_frag(const char* base, int row, int cb) {
  const int swz = (row & 7) << 4;
  const int rb  = row << 7;
  ull a = *reinterpret_cast<const ull*>(base + (rb | (cb ^ swz)));
  ull b = *reinterpret_cast<const ull*>(base + (rb | ((cb + 32) ^ swz)));
  FragU fu;
  fu.q[0] = a; fu.q[1] = b;
  return fu.f;
}

// Write one thread's two 16B staging chunks into the swizzled LDS tile.
// Thread t covers linear tile bytes [t*16, t*16+16) and [4096+t*16, ...).
static __device__ __forceinline__ void stage_write(char* dst, int t, uint4 r0, uint4 r1) {
  const int o0 = t * 16;
  const int o1 = 4096 + t * 16;
  *reinterpret_cast<uint4*>(dst + (o0 ^ (((o0 >> 7) & 7) << 4))) = r0;
  *reinterpret_cast<uint4*>(dst + (o1 ^ (((o1 >> 7) & 7) << 4))) = r1;
}

// ---------------------------------------------------------------------------
// Kernel 1: q,k,v = 1x1 conv.  qT,kT stored (B,N,64) bf16; v stored (B,64,N).
// ---------------------------------------------------------------------------
__global__ __launch_bounds__(256) void qkv_proj(
    const float* __restrict__ x,
    const float* __restrict__ Wq, const float* __restrict__ bq,
    const float* __restrict__ Wk, const float* __restrict__ bk,
    const float* __restrict__ Wv, const float* __restrict__ bv,
    unsigned short* __restrict__ qT, unsigned short* __restrict__ kT,
    unsigned short* __restrict__ vC)
{
  const int t  = threadIdx.x;
  const int b  = blockIdx.y;
  const int n  = blockIdx.x * 256 + t;
  const int o0 = blockIdx.z * 16;

  float xv[64];
  #pragma unroll
  for (int c = 0; c < 64; ++c) xv[c] = x[((size_t)b * 64 + c) * NPIX + n];

  const float* Wp[3] = {Wq, Wk, Wv};
  const float* Bp[3] = {bq, bk, bv};

  #pragma unroll
  for (int p = 0; p < 3; ++p) {
    const float* W  = Wp[p];
    const float* Bv = Bp[p];
    unsigned short outv[16];
    #pragma unroll
    for (int oo = 0; oo < 16; ++oo) {
      float acc = Bv[o0 + oo];
      #pragma unroll
      for (int c = 0; c < 64; ++c) acc += W[(o0 + oo) * 64 + c] * xv[c];
      outv[oo] = f2bf(acc);
    }
    if (p < 2) {
      unsigned short* dst = (p == 0 ? qT : kT) + ((size_t)b * NPIX + n) * 64 + o0;
      uint4 w0 = make_uint4(pack2(outv[0], outv[1]),  pack2(outv[2], outv[3]),
                            pack2(outv[4], outv[5]),  pack2(outv[6], outv[7]));
      uint4 w1 = make_uint4(pack2(outv[8], outv[9]),  pack2(outv[10], outv[11]),
                            pack2(outv[12], outv[13]), pack2(outv[14], outv[15]));
      *reinterpret_cast<uint4*>(dst)     = w0;
      *reinterpret_cast<uint4*>(dst + 8) = w1;
    } else {
      #pragma unroll
      for (int oo = 0; oo < 16; ++oo)
        vC[((size_t)b * 64 + o0 + oo) * NPIX + n] = outv[oo];
    }
  }
}

// ---------------------------------------------------------------------------
// Kernel 2: rcpZ[b,j] = 1 / sum_i exp(q_j . k_i).  LDS-staged K tiles.
// grid (64, 8): x = j-block of 64 (wave: 16 j rows), y = batch.
// ---------------------------------------------------------------------------
__global__ __launch_bounds__(256) void attn_rowsum(
    const unsigned short* __restrict__ qT, const unsigned short* __restrict__ kT,
    float* __restrict__ rcpZ)
{
  __shared__ __align__(16) char sK[2 * 8192];

  const int t    = threadIdx.x;
  const int b    = blockIdx.y;
  const int lane = t & 63;
  const int wv   = t >> 6;
  const int j0   = blockIdx.x * 64 + wv * 16;
  const int lr   = lane & 15;
  const int lg   = lane >> 4;

  const unsigned short* qrow = qT + ((size_t)b * NPIX + j0 + lr) * 64;
  const bf16x8 aq0 = load_frag(qrow, lg * 8);
  const bf16x8 aq1 = load_frag(qrow, 64 + lg * 8);

  const char* kbase = reinterpret_cast<const char*>(kT + (size_t)b * NPIX * 64);

  uint4 r0 = *reinterpret_cast<const uint4*>(kbase + t * 16);
  uint4 r1 = *reinterpret_cast<const uint4*>(kbase + 4096 + t * 16);

  float zs[4] = {0.f, 0.f, 0.f, 0.f};

  for (int tile = 0; tile < 64; ++tile) {
    char* buf = sK + (tile & 1) * 8192;
    stage_write(buf, t, r0, r1);
    __syncthreads();
    if (tile + 1 < 64) {
      const char* src = kbase + (size_t)(tile + 1) * 8192;
      r0 = *reinterpret_cast<const uint4*>(src + t * 16);
      r1 = *reinterpret_cast<const uint4*>(src + 4096 + t * 16);
    }
    #pragma unroll
    for (int f = 0; f < 4; ++f) {
      f32x4 acc = {0.f, 0.f, 0.f, 0.f};
      acc = __builtin_amdgcn_mfma_f32_16x16x32_bf16(aq0, lds_frag(buf, f * 16 + lr, lg * 8),      acc, 0, 0, 0);
      acc = __builtin_amdgcn_mfma_f32_16x16x32_bf16(aq1, lds_frag(buf, f * 16 + lr, 64 + lg * 8), acc, 0, 0, 0);
      zs[0] += __expf(acc[0]);
      zs[1] += __expf(acc[1]);
      zs[2] += __expf(acc[2]);
      zs[3] += __expf(acc[3]);
    }
    __syncthreads();
  }

  #pragma unroll
  for (int m = 8; m >= 1; m >>= 1) {
    #pragma unroll
    for (int r = 0; r < 4; ++r) zs[r] += __shfl_xor(zs[r], m, 64);
  }
  if (lr == 0) {
    const size_t base = (size_t)b * NPIX + j0 + lg * 4;
    #pragma unroll
    for (int r = 0; r < 4; ++r) rcpZ[base + r] = 1.0f / zs[r];
  }
}

// ---------------------------------------------------------------------------
// Kernel 2.5: fold 1/Z_j into V:  v'[c,j] = v[c,j] * rcpZ[j]   (in place)
// grid 1024 x 256 threads; each thread rewrites 8 consecutive shorts.
// ---------------------------------------------------------------------------
__global__ __launch_bounds__(256) void vscale(
    unsigned short* __restrict__ vC, const float* __restrict__ rcpZ)
{
  const int idx = blockIdx.x * 256 + threadIdx.x;   // 0..262143
  const int jc  = idx & 511;                        // 8-elem chunk within row
  const int b   = idx >> 15;                        // idx / (512*64)
  unsigned short* p = vC + (size_t)idx * 8;
  const float* rz = rcpZ + (size_t)b * NPIX + jc * 8;
  FragU v;
  v.q[0] = reinterpret_cast<const ull*>(p)[0];
  v.q[1] = reinterpret_cast<const ull*>(p)[1];
  #pragma unroll
  for (int e = 0; e < 8; ++e) v.s[e] = f2bf(bf2f(v.s[e]) * rz[e]);
  reinterpret_cast<ull*>(p)[0] = v.q[0];
  reinterpret_cast<ull*>(p)[1] = v.q[1];
}

// ---------------------------------------------------------------------------
// Kernel 3: res[b,c,i] = sum_j exp(q_j.k_i) * v'[c,j].  LDS-staged Q,V tiles.
// grid (64, 8): x = i-block of 64 (wave: 16 i cols), y = batch.
// ---------------------------------------------------------------------------
__global__ __launch_bounds__(256) void attn_pv(
    const unsigned short* __restrict__ qT, const unsigned short* __restrict__ kT,
    const unsigned short* __restrict__ vC,
    float* __restrict__ res)
{
  __shared__ __align__(16) char sQ[2 * 8192];
  __shared__ __align__(16) char sV[2 * 8192];

  const int t    = threadIdx.x;
  const int b    = blockIdx.y;
  const int lane = t & 63;
  const int wv   = t >> 6;
  const int i0   = blockIdx.x * 64 + wv * 16;
  const int lr   = lane & 15;
  const int lg   = lane >> 4;

  // K fragments for this wave's 16 i-columns stay in registers.
  const unsigned short* krow = kT + ((size_t)b * NPIX + i0 + lr) * 64;
  const bf16x8 bk0 = load_frag(krow, lg * 8);
  const bf16x8 bk1 = load_frag(krow, 64 + lg * 8);

  f32x4 acc[4];
  #pragma unroll
  for (int m = 0; m < 4; ++m) acc[m] = (f32x4){0.f, 0.f, 0.f, 0.f};

  const char* qbase = reinterpret_cast<const char*>(qT + (size_t)b * NPIX * 64);
  const char* vbase = reinterpret_cast<const char*>(vC + (size_t)b * 64 * NPIX);

  // V staging source addresses: tile rows are channels (row stride 8192B),
  // 128B of j per row per tile.
  const int vo0_row = (t * 16) >> 7,        vo0_col = (t * 16) & 127;
  const int vo1_row = (4096 + t * 16) >> 7, vo1_col = (4096 + t * 16) & 127;

  uint4 q0 = *reinterpret_cast<const uint4*>(qbase + t * 16);
  uint4 q1 = *reinterpret_cast<const uint4*>(qbase + 4096 + t * 16);
  uint4 v0 = *reinterpret_cast<const uint4*>(vbase + (size_t)vo0_row * 8192 + vo0_col);
  uint4 v1 = *reinterpret_cast<const uint4*>(vbase + (size_t)vo1_row * 8192 + vo1_col);

  for (int tile = 0; tile < 64; ++tile) {
    char* Qt = sQ + (tile & 1) * 8192;
    char* Vt = sV + (tile & 1) * 8192;
    stage_write(Qt, t, q0, q1);
    stage_write(Vt, t, v0, v1);
    __syncthreads();
    if (tile + 1 < 64) {
      const char* qsrc = qbase + (size_t)(tile + 1) * 8192;
      q0 = *reinterpret_cast<const uint4*>(qsrc + t * 16);
      q1 = *reinterpret_cast<const uint4*>(qsrc + 4096 + t * 16);
      const int jb = (tile + 1) * 128;
      v0 = *reinterpret_cast<const uint4*>(vbase + (size_t)vo0_row * 8192 + jb + vo0_col);
      v1 = *reinterpret_cast<const uint4*>(vbase + (size_t)vo1_row * 8192 + jb + vo1_col);
    }

    // S = Q-tile (64 j rows) x this wave's 16 i cols
    f32x4 s[4];
    #pragma unroll
    for (int f = 0; f < 4; ++f) {
      s[f] = (f32x4){0.f, 0.f, 0.f, 0.f};
      s[f] = __builtin_amdgcn_mfma_f32_16x16x32_bf16(lds_frag(Qt, f * 16 + lr, lg * 8),      bk0, s[f], 0, 0, 0);
      s[f] = __builtin_amdgcn_mfma_f32_16x16x32_bf16(lds_frag(Qt, f * 16 + lr, 64 + lg * 8), bk1, s[f], 0, 0, 0);
    }

    FragU pe0, pe1;
    #pragma unroll
    for (int r = 0; r < 4; ++r) {
      pe0.s[r]     = f2bf(__expf(s[0][r]));
      pe0.s[4 + r] = f2bf(__expf(s[1][r]));
      pe1.s[r]     = f2bf(__expf(s[2][r]));
      pe1.s[4 + r] = f2bf(__expf(s[3][r]));
    }

    #pragma unroll
    for (int m = 0; m < 4; ++m) {
      bf16x8 av0 = lds_frag(Vt, m * 16 + lr, lg * 8);
      acc[m] = __builtin_amdgcn_mfma_f32_16x16x32_bf16(av0, pe0.f, acc[m], 0, 0, 0);
      bf16x8 av1 = lds_frag(Vt, m * 16 + lr, 64 + lg * 8);
      acc[m] = __builtin_amdgcn_mfma_f32_16x16x32_bf16(av1, pe1.f, acc[m], 0, 0, 0);
    }
    __syncthreads();
  }

  #pragma unroll
  for (int m = 0; m < 4; ++m) {
    #pragma unroll
    for (int r = 0; r < 4; ++r) {
      res[((size_t)b * 64 + m * 16 + lg * 4 + r) * NPIX + i0 + lr] = acc[m][r];
    }
  }
}

// ---------------------------------------------------------------------------
// Kernel 4: out = Wo*res + bo + res.
// ---------------------------------------------------------------------------
__global__ __launch_bounds__(256) void out_proj(
    const float* __restrict__ res, const float* __restrict__ Wo,
    const float* __restrict__ bo, float* __restrict__ out)
{
  const int t  = threadIdx.x;
  const int b  = blockIdx.y;
  const int n  = blockIdx.x * 256 + t;
  const int o0 = blockIdx.z * 16;

  float rv[64];
  #pragma unroll
  for (int c = 0; c < 64; ++c) rv[c] = res[((size_t)b * 64 + c) * NPIX + n];

  #pragma unroll
  for (int oo = 0; oo < 16; ++oo) {
    float acc = bo[o0 + oo];
    #pragma unroll
    for (int c = 0; c < 64; ++c) acc += Wo[(o0 + oo) * 64 + c] * rv[c];
    acc += res[((size_t)b * 64 + o0 + oo) * NPIX + n];
    out[((size_t)b * 64 + o0 + oo) * NPIX + n] = acc;
  }
}

// ---------------------------------------------------------------------------
extern "C" void kernel_launch(void* const* d_in, const int* in_sizes, int n_in,
                              void* d_out, int out_size, void* d_ws, size_t ws_size,
                              hipStream_t stream) {
  const float* x  = (const float*)d_in[0];
  const float* Wq = (const float*)d_in[1];
  const float* bq = (const float*)d_in[2];
  const float* Wk = (const float*)d_in[3];
  const float* bk = (const float*)d_in[4];
  const float* Wv = (const float*)d_in[5];
  const float* bv = (const float*)d_in[6];
  const float* Wo = (const float*)d_in[7];
  const float* bo = (const float*)d_in[8];
  float* out = (float*)d_out;

  char* ws = (char*)d_ws;
  unsigned short* qT = (unsigned short*)(ws);                         // 4 MB
  unsigned short* kT = (unsigned short*)(ws + ((size_t)4 << 20));     // 4 MB
  unsigned short* vC = (unsigned short*)(ws + ((size_t)8 << 20));     // 4 MB
  float* rcpZ        = (float*)(ws + ((size_t)12 << 20));             // 128 KB
  float* res         = (float*)(ws + ((size_t)12 << 20) + (1 << 17)); // 8 MB

  qkv_proj<<<dim3(16, 8, 4), 256, 0, stream>>>(x, Wq, bq, Wk, bk, Wv, bv, qT, kT, vC);
  attn_rowsum<<<dim3(64, 8), 256, 0, stream>>>(qT, kT, rcpZ);
  vscale<<<dim3(1024), 256, 0, stream>>>(vC, rcpZ);
  attn_pv<<<dim3(64, 8), 256, 0, stream>>>(qT, kT, vC, res);
  out_proj<<<dim3(16, 8, 4), 256, 0, stream>>>(res, Wo, bo, out);
}

// Round 5
// 267.711 us; speedup vs baseline: 3.0259x; 1.0352x over previous
//
#include <hip/hip_runtime.h>
#include <stdint.h>

#define NPIX 4096

typedef __bf16 bf16x8 __attribute__((ext_vector_type(8)));
typedef float  f32x4  __attribute__((ext_vector_type(4)));
typedef unsigned long long ull;

union FragU {
  bf16x8 f;
  uint4  u;
  ull    q[2];
  unsigned short s[8];
};

static __device__ __forceinline__ unsigned short f2bf(float x) {
  unsigned int u = __float_as_uint(x);
  u += 0x7FFFu + ((u >> 16) & 1u);
  return (unsigned short)(u >> 16);
}
static __device__ __forceinline__ float bf2f(unsigned short s) {
  return __uint_as_float(((unsigned int)s) << 16);
}
static __device__ __forceinline__ unsigned int pack2(unsigned short a, unsigned short b) {
  return (unsigned int)a | ((unsigned int)b << 16);
}

// Global-memory fragment load (16x16x32 A/B layout: 8B at byteOff, 8B at +32).
// VERIFIED layout (rounds 1-2, absmax 0.5).
static __device__ __forceinline__ bf16x8 load_frag(const unsigned short* base, int byteOff) {
  const char* p = reinterpret_cast<const char*>(base) + byteOff;
  uint2 a = *reinterpret_cast<const uint2*>(p);
  uint2 b = *reinterpret_cast<const uint2*>(p + 32);
  FragU fu;
  fu.u = make_uint4(a.x, a.y, b.x, b.y);
  return fu.f;
}

// LDS fragment load from a 64x64-short tile, row-major 128B rows,
// byte-swizzle L = P ^ ((row&7)<<4).  VERIFIED (round 2).
static __device__ __forceinline__ bf16x8 lds_frag(const char* base, int row, int cb) {
  const int swz = (row & 7) << 4;
  const int rb  = row << 7;
  ull a = *reinterpret_cast<const ull*>(base + (rb | (cb ^ swz)));
  ull b = *reinterpret_cast<const ull*>(base + (rb | ((cb + 32) ^ swz)));
  FragU fu;
  fu.q[0] = a; fu.q[1] = b;
  return fu.f;
}

// Thread t stages linear tile bytes [t*16, +16) and [4096+t*16, +16). VERIFIED.
static __device__ __forceinline__ void stage_write(char* dst, int t, uint4 r0, uint4 r1) {
  const int o0 = t * 16;
  const int o1 = 4096 + t * 16;
  *reinterpret_cast<uint4*>(dst + (o0 ^ (((o0 >> 7) & 7) << 4))) = r0;
  *reinterpret_cast<uint4*>(dst + (o1 ^ (((o1 >> 7) & 7) << 4))) = r1;
}

// ---------------------------------------------------------------------------
// Kernel 1: q,k,v = 1x1 conv.  qT,kT stored (B,N,64) bf16; v stored (B,64,N).
// VERBATIM round 2 (verified).
// ---------------------------------------------------------------------------
__global__ __launch_bounds__(256) void qkv_proj(
    const float* __restrict__ x,
    const float* __restrict__ Wq, const float* __restrict__ bq,
    const float* __restrict__ Wk, const float* __restrict__ bk,
    const float* __restrict__ Wv, const float* __restrict__ bv,
    unsigned short* __restrict__ qT, unsigned short* __restrict__ kT,
    unsigned short* __restrict__ vC)
{
  const int t  = threadIdx.x;
  const int b  = blockIdx.y;
  const int n  = blockIdx.x * 256 + t;
  const int o0 = blockIdx.z * 16;

  float xv[64];
  #pragma unroll
  for (int c = 0; c < 64; ++c) xv[c] = x[((size_t)b * 64 + c) * NPIX + n];

  const float* Wp[3] = {Wq, Wk, Wv};
  const float* Bp[3] = {bq, bk, bv};

  #pragma unroll
  for (int p = 0; p < 3; ++p) {
    const float* W  = Wp[p];
    const float* Bv = Bp[p];
    unsigned short outv[16];
    #pragma unroll
    for (int oo = 0; oo < 16; ++oo) {
      float acc = Bv[o0 + oo];
      #pragma unroll
      for (int c = 0; c < 64; ++c) acc += W[(o0 + oo) * 64 + c] * xv[c];
      outv[oo] = f2bf(acc);
    }
    if (p < 2) {
      unsigned short* dst = (p == 0 ? qT : kT) + ((size_t)b * NPIX + n) * 64 + o0;
      uint4 w0 = make_uint4(pack2(outv[0], outv[1]),  pack2(outv[2], outv[3]),
                            pack2(outv[4], outv[5]),  pack2(outv[6], outv[7]));
      uint4 w1 = make_uint4(pack2(outv[8], outv[9]),  pack2(outv[10], outv[11]),
                            pack2(outv[12], outv[13]), pack2(outv[14], outv[15]));
      *reinterpret_cast<uint4*>(dst)     = w0;
      *reinterpret_cast<uint4*>(dst + 8) = w1;
    } else {
      #pragma unroll
      for (int oo = 0; oo < 16; ++oo)
        vC[((size_t)b * 64 + o0 + oo) * NPIX + n] = outv[oo];
    }
  }
}

// ---------------------------------------------------------------------------
// Kernel 2: Zpart[part][b][j] = sum over this part's i of exp(q_j . k_i).
// grid (16, 8, nparts): wave owns 64 j rows (4 f-strips); K tiles LDS-staged.
// ---------------------------------------------------------------------------
__global__ __launch_bounds__(256, 2) void attn_rowsum(
    const unsigned short* __restrict__ qT, const unsigned short* __restrict__ kT,
    float* __restrict__ Zpart, int ntiles)
{
  __shared__ __align__(16) char sK[2 * 8192];

  const int t    = threadIdx.x;
  const int b    = blockIdx.y;
  const int part = blockIdx.z;
  const int lane = t & 63;
  const int wv   = t >> 6;
  const int j0   = blockIdx.x * 256 + wv * 64;
  const int lr   = lane & 15;
  const int lg   = lane >> 4;

  // Q fragments (A-operand) for this wave's 64 j rows.
  bf16x8 aq0[4], aq1[4];
  #pragma unroll
  for (int f = 0; f < 4; ++f) {
    const unsigned short* qrow = qT + ((size_t)b * NPIX + j0 + f * 16 + lr) * 64;
    aq0[f] = load_frag(qrow, lg * 8);
    aq1[f] = load_frag(qrow, 64 + lg * 8);
  }

  const char* kbase = reinterpret_cast<const char*>(kT) + (size_t)b * NPIX * 128
                      + (size_t)part * ntiles * 8192;

  float zacc[4][4];
  #pragma unroll
  for (int f = 0; f < 4; ++f)
    #pragma unroll
    for (int r = 0; r < 4; ++r) zacc[f][r] = 0.f;

  uint4 r0 = *reinterpret_cast<const uint4*>(kbase + t * 16);
  uint4 r1 = *reinterpret_cast<const uint4*>(kbase + 4096 + t * 16);

  for (int tile = 0; tile < ntiles; ++tile) {
    char* buf = sK + (tile & 1) * 8192;
    stage_write(buf, t, r0, r1);
    __syncthreads();
    if (tile + 1 < ntiles) {
      const char* src = kbase + (size_t)(tile + 1) * 8192;
      r0 = *reinterpret_cast<const uint4*>(src + t * 16);
      r1 = *reinterpret_cast<const uint4*>(src + 4096 + t * 16);
    }
    bf16x8 kf0[4], kf1[4];
    #pragma unroll
    for (int s = 0; s < 4; ++s) {
      kf0[s] = lds_frag(buf, s * 16 + lr, lg * 8);
      kf1[s] = lds_frag(buf, s * 16 + lr, 64 + lg * 8);
    }
    #pragma unroll
    for (int f = 0; f < 4; ++f) {
      #pragma unroll
      for (int s = 0; s < 4; ++s) {
        f32x4 S = {0.f, 0.f, 0.f, 0.f};
        S = __builtin_amdgcn_mfma_f32_16x16x32_bf16(aq0[f], kf0[s], S, 0, 0, 0);
        S = __builtin_amdgcn_mfma_f32_16x16x32_bf16(aq1[f], kf1[s], S, 0, 0, 0);
        zacc[f][0] += __expf(S[0]);
        zacc[f][1] += __expf(S[1]);
        zacc[f][2] += __expf(S[2]);
        zacc[f][3] += __expf(S[3]);
      }
    }
    __syncthreads();
  }

  #pragma unroll
  for (int f = 0; f < 4; ++f) {
    #pragma unroll
    for (int m = 8; m >= 1; m >>= 1) {
      #pragma unroll
      for (int r = 0; r < 4; ++r) zacc[f][r] += __shfl_xor(zacc[f][r], m, 64);
    }
  }
  if (lr == 0) {
    float* dst = Zpart + ((size_t)part * 8 + b) * NPIX + j0 + lg * 4;
    #pragma unroll
    for (int f = 0; f < 4; ++f) {
      #pragma unroll
      for (int r = 0; r < 4; ++r) dst[f * 16 + r] = zacc[f][r];
    }
  }
}

// ---------------------------------------------------------------------------
// Kernel 2.4: rcpZ = 1 / sum_p Zpart.   grid 128 x 256.
// ---------------------------------------------------------------------------
__global__ __launch_bounds__(256) void zred(
    const float* __restrict__ Zpart, float* __restrict__ rcpZ, int nparts)
{
  const int idx = blockIdx.x * 256 + threadIdx.x;   // b*4096 + j
  float z = 0.f;
  for (int p = 0; p < nparts; ++p) z += Zpart[(size_t)p * 8 * NPIX + idx];
  rcpZ[idx] = 1.0f / z;
}

// ---------------------------------------------------------------------------
// Kernel 2.5: v'[c,n] = v[c,n] * rcpZ[n]  (linear layout, in place).
// VERBATIM round 2 (verified).
// ---------------------------------------------------------------------------
__global__ __launch_bounds__(256) void vscale(
    unsigned short* __restrict__ vC, const float* __restrict__ rcpZ)
{
  const int idx = blockIdx.x * 256 + threadIdx.x;   // 0..262143
  const int jc  = idx & 511;
  const int b   = idx >> 15;
  unsigned short* p = vC + (size_t)idx * 8;
  const float* rz = rcpZ + (size_t)b * NPIX + jc * 8;
  FragU v;
  v.q[0] = reinterpret_cast<const ull*>(p)[0];
  v.q[1] = reinterpret_cast<const ull*>(p)[1];
  #pragma unroll
  for (int e = 0; e < 8; ++e) v.s[e] = f2bf(bf2f(v.s[e]) * rz[e]);
  reinterpret_cast<ull*>(p)[0] = v.q[0];
  reinterpret_cast<ull*>(p)[1] = v.q[1];
}

// ---------------------------------------------------------------------------
// Kernel 3: resP[part][b][c][i] = sum over part's j of exp(q_j.k_i)*v'[c,j].
// grid (16, 8, nparts). Wave owns i=64 (4 s-strips); Q,V tiles LDS-staged,
// fragments read once per tile and reused across the 4 strips.
// ---------------------------------------------------------------------------
__global__ __launch_bounds__(256, 2) void attn_pv(
    const unsigned short* __restrict__ qT, const unsigned short* __restrict__ kT,
    const unsigned short* __restrict__ vC, float* __restrict__ resP, int ntiles)
{
  __shared__ __align__(16) char sQ[2 * 8192];
  __shared__ __align__(16) char sV[2 * 8192];

  const int t    = threadIdx.x;
  const int b    = blockIdx.y;
  const int part = blockIdx.z;
  const int lane = t & 63;
  const int wv   = t >> 6;
  const int i0   = blockIdx.x * 256 + wv * 64;
  const int lr   = lane & 15;
  const int lg   = lane >> 4;
  const int jstart = part * ntiles * 64;

  // K fragments (B-operand) for the wave's 64 i columns, in regs all kernel.
  bf16x8 kf0[4], kf1[4];
  #pragma unroll
  for (int s = 0; s < 4; ++s) {
    const unsigned short* krow = kT + ((size_t)b * NPIX + i0 + s * 16 + lr) * 64;
    kf0[s] = load_frag(krow, lg * 8);
    kf1[s] = load_frag(krow, 64 + lg * 8);
  }

  const char* qbase = reinterpret_cast<const char*>(qT) + ((size_t)b * NPIX + jstart) * 128;
  const char* vbase = reinterpret_cast<const char*>(vC) + (size_t)b * 64 * 8192
                      + (size_t)jstart * 2;

  const int vo0_row = (t * 16) >> 7,        vo0_col = (t * 16) & 127;
  const int vo1_row = (4096 + t * 16) >> 7, vo1_col = (4096 + t * 16) & 127;

  f32x4 acc[4][4];
  #pragma unroll
  for (int m = 0; m < 4; ++m)
    #pragma unroll
    for (int s = 0; s < 4; ++s) acc[m][s] = (f32x4){0.f, 0.f, 0.f, 0.f};

  uint4 q0 = *reinterpret_cast<const uint4*>(qbase + t * 16);
  uint4 q1 = *reinterpret_cast<const uint4*>(qbase + 4096 + t * 16);
  uint4 v0 = *reinterpret_cast<const uint4*>(vbase + (size_t)vo0_row * 8192 + vo0_col);
  uint4 v1 = *reinterpret_cast<const uint4*>(vbase + (size_t)vo1_row * 8192 + vo1_col);

  for (int tile = 0; tile < ntiles; ++tile) {
    char* Qt = sQ + (tile & 1) * 8192;
    char* Vt = sV + (tile & 1) * 8192;
    stage_write(Qt, t, q0, q1);
    stage_write(Vt, t, v0, v1);
    __syncthreads();
    if (tile + 1 < ntiles) {
      const char* qsrc = qbase + (size_t)(tile + 1) * 8192;
      q0 = *reinterpret_cast<const uint4*>(qsrc + t * 16);
      q1 = *reinterpret_cast<const uint4*>(qsrc + 4096 + t * 16);
      const int jb = (tile + 1) * 128;
      v0 = *reinterpret_cast<const uint4*>(vbase + (size_t)vo0_row * 8192 + jb + vo0_col);
      v1 = *reinterpret_cast<const uint4*>(vbase + (size_t)vo1_row * 8192 + jb + vo1_col);
    }

    // Fragments read ONCE per tile, reused across the 4 i-strips.
    bf16x8 qf0[4], qf1[4], vf0[4], vf1[4];
    #pragma unroll
    for (int f = 0; f < 4; ++f) {
      qf0[f] = lds_frag(Qt, f * 16 + lr, lg * 8);
      qf1[f] = lds_frag(Qt, f * 16 + lr, 64 + lg * 8);
    }
    #pragma unroll
    for (int m = 0; m < 4; ++m) {
      vf0[m] = lds_frag(Vt, m * 16 + lr, lg * 8);
      vf1[m] = lds_frag(Vt, m * 16 + lr, 64 + lg * 8);
    }

    #pragma unroll
    for (int s = 0; s < 4; ++s) {
      f32x4 sj[4];
      #pragma unroll
      for (int f = 0; f < 4; ++f) {
        sj[f] = (f32x4){0.f, 0.f, 0.f, 0.f};
        sj[f] = __builtin_amdgcn_mfma_f32_16x16x32_bf16(qf0[f], kf0[s], sj[f], 0, 0, 0);
        sj[f] = __builtin_amdgcn_mfma_f32_16x16x32_bf16(qf1[f], kf1[s], sj[f], 0, 0, 0);
      }
      FragU pe0, pe1;
      #pragma unroll
      for (int r = 0; r < 4; ++r) {
        pe0.s[r]     = f2bf(__expf(sj[0][r]));
        pe0.s[4 + r] = f2bf(__expf(sj[1][r]));
        pe1.s[r]     = f2bf(__expf(sj[2][r]));
        pe1.s[4 + r] = f2bf(__expf(sj[3][r]));
      }
      #pragma unroll
      for (int m = 0; m < 4; ++m) {
        acc[m][s] = __builtin_amdgcn_mfma_f32_16x16x32_bf16(vf0[m], pe0.f, acc[m][s], 0, 0, 0);
        acc[m][s] = __builtin_amdgcn_mfma_f32_16x16x32_bf16(vf1[m], pe1.f, acc[m][s], 0, 0, 0);
      }
    }
    __syncthreads();
  }

  float* rbase = resP + ((size_t)part * 8 + b) * 64 * NPIX;
  #pragma unroll
  for (int m = 0; m < 4; ++m) {
    #pragma unroll
    for (int s = 0; s < 4; ++s) {
      #pragma unroll
      for (int r = 0; r < 4; ++r) {
        rbase[(size_t)(m * 16 + lg * 4 + r) * NPIX + i0 + s * 16 + lr] = acc[m][s][r];
      }
    }
  }
}

// ---------------------------------------------------------------------------
// Kernel 4: res = sum_p resP;  out = Wo*res + bo + res.   grid (32, 8) x 128.
// ---------------------------------------------------------------------------
__global__ __launch_bounds__(128) void out_proj(
    const float* __restrict__ resP, const float* __restrict__ Wo,
    const float* __restrict__ bo, float* __restrict__ out, int nparts)
{
  const int t = threadIdx.x;
  const int b = blockIdx.y;
  const int n = blockIdx.x * 128 + t;

  float rv[64];
  #pragma unroll
  for (int c = 0; c < 64; ++c) rv[c] = 0.f;
  for (int p = 0; p < nparts; ++p) {
    const float* base = resP + ((size_t)p * 8 + b) * 64 * NPIX + n;
    #pragma unroll
    for (int c = 0; c < 64; ++c) rv[c] += base[(size_t)c * NPIX];
  }

  #pragma unroll
  for (int o = 0; o < 64; ++o) {
    float acc = bo[o];
    #pragma unroll
    for (int c = 0; c < 64; ++c) acc += Wo[o * 64 + c] * rv[c];
    out[((size_t)b * 64 + o) * NPIX + n] = acc + rv[o];
  }
}

// ---------------------------------------------------------------------------
extern "C" void kernel_launch(void* const* d_in, const int* in_sizes, int n_in,
                              void* d_out, int out_size, void* d_ws, size_t ws_size,
                              hipStream_t stream) {
  const float* x  = (const float*)d_in[0];
  const float* Wq = (const float*)d_in[1];
  const float* bq = (const float*)d_in[2];
  const float* Wk = (const float*)d_in[3];
  const float* bk = (const float*)d_in[4];
  const float* Wv = (const float*)d_in[5];
  const float* bv = (const float*)d_in[6];
  const float* Wo = (const float*)d_in[7];
  const float* bo = (const float*)d_in[8];
  float* out = (float*)d_out;

  char* ws = (char*)d_ws;
  unsigned short* qT = (unsigned short*)(ws);                          // 4 MB
  unsigned short* kT = (unsigned short*)(ws + ((size_t)4 << 20));      // 4 MB
  unsigned short* vC = (unsigned short*)(ws + ((size_t)8 << 20));      // 4 MB
  float* Zpart       = (float*)(ws + ((size_t)12 << 20));              // <=512 KB
  float* rcpZ        = (float*)(ws + ((size_t)12 << 20) + (512 << 10));// 128 KB
  float* resP        = (float*)(ws + ((size_t)13 << 20));              // nparts*8 MB

  int nparts;
  const size_t MB = (size_t)1 << 20;
  if      (ws_size >= 13 * MB + 4 * 8 * MB) nparts = 4;
  else if (ws_size >= 13 * MB + 2 * 8 * MB) nparts = 2;
  else                                      nparts = 1;
  const int ntiles = 64 / nparts;

  qkv_proj<<<dim3(16, 8, 4), 256, 0, stream>>>(x, Wq, bq, Wk, bk, Wv, bv, qT, kT, vC);
  attn_rowsum<<<dim3(16, 8, nparts), 256, 0, stream>>>(qT, kT, Zpart, ntiles);
  zred<<<dim3(128), 256, 0, stream>>>(Zpart, rcpZ, nparts);
  vscale<<<dim3(1024), 256, 0, stream>>>(vC, rcpZ);
  attn_pv<<<dim3(16, 8, nparts), 256, 0, stream>>>(qT, kT, vC, resP, ntiles);
  out_proj<<<dim3(32, 8), 128, 0, stream>>>(resP, Wo, bo, out, nparts);
}

// Round 6
// 227.249 us; speedup vs baseline: 3.5647x; 1.1780x over previous
//
#include <hip/hip_runtime.h>
#include <stdint.h>

#define NPIX 4096

typedef __bf16 bf16x8 __attribute__((ext_vector_type(8)));
typedef float  f32x4  __attribute__((ext_vector_type(4)));
typedef unsigned long long ull;

union FragU {
  bf16x8 f;
  uint4  u;
  ull    q[2];
  unsigned short s[8];
};

static __device__ __forceinline__ unsigned short f2bf(float x) {
  unsigned int u = __float_as_uint(x);
  u += 0x7FFFu + ((u >> 16) & 1u);
  return (unsigned short)(u >> 16);
}
static __device__ __forceinline__ float bf2f(unsigned short s) {
  return __uint_as_float(((unsigned int)s) << 16);
}
static __device__ __forceinline__ unsigned int pack2(unsigned short a, unsigned short b) {
  return (unsigned int)a | ((unsigned int)b << 16);
}

// Global-memory fragment load (16x16x32 A/B layout: 8B at byteOff, 8B at +32).
// VERIFIED layout (rounds 1-2-5, absmax 0.5).
static __device__ __forceinline__ bf16x8 load_frag(const unsigned short* base, int byteOff) {
  const char* p = reinterpret_cast<const char*>(base) + byteOff;
  uint2 a = *reinterpret_cast<const uint2*>(p);
  uint2 b = *reinterpret_cast<const uint2*>(p + 32);
  FragU fu;
  fu.u = make_uint4(a.x, a.y, b.x, b.y);
  return fu.f;
}

// LDS fragment load from a 64x64-short tile, row-major 128B rows,
// byte-swizzle L = P ^ ((row&7)<<4).  VERIFIED (rounds 2, 5).
static __device__ __forceinline__ bf16x8 lds_frag(const char* base, int row, int cb) {
  const int swz = (row & 7) << 4;
  const int rb  = row << 7;
  ull a = *reinterpret_cast<const ull*>(base + (rb | (cb ^ swz)));
  ull b = *reinterpret_cast<const ull*>(base + (rb | ((cb + 32) ^ swz)));
  FragU fu;
  fu.q[0] = a; fu.q[1] = b;
  return fu.f;
}

// Thread t stages linear tile bytes [t*16, +16) and [4096+t*16, +16). VERIFIED.
static __device__ __forceinline__ void stage_write(char* dst, int t, uint4 r0, uint4 r1) {
  const int o0 = t * 16;
  const int o1 = 4096 + t * 16;
  *reinterpret_cast<uint4*>(dst + (o0 ^ (((o0 >> 7) & 7) << 4))) = r0;
  *reinterpret_cast<uint4*>(dst + (o1 ^ (((o1 >> 7) & 7) << 4))) = r1;
}

// ---------------------------------------------------------------------------
// Kernel 1: q,k,v = 1x1 conv.  qT,kT stored (B,N,64) bf16; v stored (B,64,N).
// VERBATIM round 2/5 (verified).
// ---------------------------------------------------------------------------
__global__ __launch_bounds__(256) void qkv_proj(
    const float* __restrict__ x,
    const float* __restrict__ Wq, const float* __restrict__ bq,
    const float* __restrict__ Wk, const float* __restrict__ bk,
    const float* __restrict__ Wv, const float* __restrict__ bv,
    unsigned short* __restrict__ qT, unsigned short* __restrict__ kT,
    unsigned short* __restrict__ vC)
{
  const int t  = threadIdx.x;
  const int b  = blockIdx.y;
  const int n  = blockIdx.x * 256 + t;
  const int o0 = blockIdx.z * 16;

  float xv[64];
  #pragma unroll
  for (int c = 0; c < 64; ++c) xv[c] = x[((size_t)b * 64 + c) * NPIX + n];

  const float* Wp[3] = {Wq, Wk, Wv};
  const float* Bp[3] = {bq, bk, bv};

  #pragma unroll
  for (int p = 0; p < 3; ++p) {
    const float* W  = Wp[p];
    const float* Bv = Bp[p];
    unsigned short outv[16];
    #pragma unroll
    for (int oo = 0; oo < 16; ++oo) {
      float acc = Bv[o0 + oo];
      #pragma unroll
      for (int c = 0; c < 64; ++c) acc += W[(o0 + oo) * 64 + c] * xv[c];
      outv[oo] = f2bf(acc);
    }
    if (p < 2) {
      unsigned short* dst = (p == 0 ? qT : kT) + ((size_t)b * NPIX + n) * 64 + o0;
      uint4 w0 = make_uint4(pack2(outv[0], outv[1]),  pack2(outv[2], outv[3]),
                            pack2(outv[4], outv[5]),  pack2(outv[6], outv[7]));
      uint4 w1 = make_uint4(pack2(outv[8], outv[9]),  pack2(outv[10], outv[11]),
                            pack2(outv[12], outv[13]), pack2(outv[14], outv[15]));
      *reinterpret_cast<uint4*>(dst)     = w0;
      *reinterpret_cast<uint4*>(dst + 8) = w1;
    } else {
      #pragma unroll
      for (int oo = 0; oo < 16; ++oo)
        vC[((size_t)b * 64 + o0 + oo) * NPIX + n] = outv[oo];
    }
  }
}

// ---------------------------------------------------------------------------
// Kernel 2: Zpart[part][b][j] = sum over this part's i of exp(q_j . k_i).
// VERBATIM round 5 (verified).
// ---------------------------------------------------------------------------
__global__ __launch_bounds__(256, 2) void attn_rowsum(
    const unsigned short* __restrict__ qT, const unsigned short* __restrict__ kT,
    float* __restrict__ Zpart, int ntiles)
{
  __shared__ __align__(16) char sK[2 * 8192];

  const int t    = threadIdx.x;
  const int b    = blockIdx.y;
  const int part = blockIdx.z;
  const int lane = t & 63;
  const int wv   = t >> 6;
  const int j0   = blockIdx.x * 256 + wv * 64;
  const int lr   = lane & 15;
  const int lg   = lane >> 4;

  bf16x8 aq0[4], aq1[4];
  #pragma unroll
  for (int f = 0; f < 4; ++f) {
    const unsigned short* qrow = qT + ((size_t)b * NPIX + j0 + f * 16 + lr) * 64;
    aq0[f] = load_frag(qrow, lg * 8);
    aq1[f] = load_frag(qrow, 64 + lg * 8);
  }

  const char* kbase = reinterpret_cast<const char*>(kT) + (size_t)b * NPIX * 128
                      + (size_t)part * ntiles * 8192;

  float zacc[4][4];
  #pragma unroll
  for (int f = 0; f < 4; ++f)
    #pragma unroll
    for (int r = 0; r < 4; ++r) zacc[f][r] = 0.f;

  uint4 r0 = *reinterpret_cast<const uint4*>(kbase + t * 16);
  uint4 r1 = *reinterpret_cast<const uint4*>(kbase + 4096 + t * 16);

  for (int tile = 0; tile < ntiles; ++tile) {
    char* buf = sK + (tile & 1) * 8192;
    stage_write(buf, t, r0, r1);
    __syncthreads();
    if (tile + 1 < ntiles) {
      const char* src = kbase + (size_t)(tile + 1) * 8192;
      r0 = *reinterpret_cast<const uint4*>(src + t * 16);
      r1 = *reinterpret_cast<const uint4*>(src + 4096 + t * 16);
    }
    bf16x8 kf0[4], kf1[4];
    #pragma unroll
    for (int s = 0; s < 4; ++s) {
      kf0[s] = lds_frag(buf, s * 16 + lr, lg * 8);
      kf1[s] = lds_frag(buf, s * 16 + lr, 64 + lg * 8);
    }
    #pragma unroll
    for (int f = 0; f < 4; ++f) {
      #pragma unroll
      for (int s = 0; s < 4; ++s) {
        f32x4 S = {0.f, 0.f, 0.f, 0.f};
        S = __builtin_amdgcn_mfma_f32_16x16x32_bf16(aq0[f], kf0[s], S, 0, 0, 0);
        S = __builtin_amdgcn_mfma_f32_16x16x32_bf16(aq1[f], kf1[s], S, 0, 0, 0);
        zacc[f][0] += __expf(S[0]);
        zacc[f][1] += __expf(S[1]);
        zacc[f][2] += __expf(S[2]);
        zacc[f][3] += __expf(S[3]);
      }
    }
    __syncthreads();
  }

  #pragma unroll
  for (int f = 0; f < 4; ++f) {
    #pragma unroll
    for (int m = 8; m >= 1; m >>= 1) {
      #pragma unroll
      for (int r = 0; r < 4; ++r) zacc[f][r] += __shfl_xor(zacc[f][r], m, 64);
    }
  }
  if (lr == 0) {
    float* dst = Zpart + ((size_t)part * 8 + b) * NPIX + j0 + lg * 4;
    #pragma unroll
    for (int f = 0; f < 4; ++f) {
      #pragma unroll
      for (int r = 0; r < 4; ++r) dst[f * 16 + r] = zacc[f][r];
    }
  }
}

// ---------------------------------------------------------------------------
// Kernel 2.5 (fused zred+vscale): v'[c,n] = v[c,n] / sum_p Zpart[p][b][n].
// Zpart is 512 KB -> L2-resident; per-thread 32 extra L2 loads.
// ---------------------------------------------------------------------------
__global__ __launch_bounds__(256) void vscale(
    unsigned short* __restrict__ vC, const float* __restrict__ Zpart, int nparts)
{
  const int idx = blockIdx.x * 256 + threadIdx.x;   // 0..262143
  const int jc  = idx & 511;
  const int b   = idx >> 15;
  unsigned short* p = vC + (size_t)idx * 8;
  const float* zb = Zpart + (size_t)b * NPIX + jc * 8;
  float z[8];
  #pragma unroll
  for (int e = 0; e < 8; ++e) z[e] = 0.f;
  for (int pp = 0; pp < nparts; ++pp) {
    const float* zp = zb + (size_t)pp * 8 * NPIX;
    #pragma unroll
    for (int e = 0; e < 8; ++e) z[e] += zp[e];
  }
  FragU v;
  v.q[0] = reinterpret_cast<const ull*>(p)[0];
  v.q[1] = reinterpret_cast<const ull*>(p)[1];
  #pragma unroll
  for (int e = 0; e < 8; ++e) v.s[e] = f2bf(bf2f(v.s[e]) * (1.0f / z[e]));
  reinterpret_cast<ull*>(p)[0] = v.q[0];
  reinterpret_cast<ull*>(p)[1] = v.q[1];
}

// ---------------------------------------------------------------------------
// Kernel 3: resP[part][b][c][i] = sum over part's j of exp(q_j.k_i)*v'[c,j].
// VERBATIM round 5 (verified).
// ---------------------------------------------------------------------------
__global__ __launch_bounds__(256, 2) void attn_pv(
    const unsigned short* __restrict__ qT, const unsigned short* __restrict__ kT,
    const unsigned short* __restrict__ vC, float* __restrict__ resP, int ntiles)
{
  __shared__ __align__(16) char sQ[2 * 8192];
  __shared__ __align__(16) char sV[2 * 8192];

  const int t    = threadIdx.x;
  const int b    = blockIdx.y;
  const int part = blockIdx.z;
  const int lane = t & 63;
  const int wv   = t >> 6;
  const int i0   = blockIdx.x * 256 + wv * 64;
  const int lr   = lane & 15;
  const int lg   = lane >> 4;
  const int jstart = part * ntiles * 64;

  bf16x8 kf0[4], kf1[4];
  #pragma unroll
  for (int s = 0; s < 4; ++s) {
    const unsigned short* krow = kT + ((size_t)b * NPIX + i0 + s * 16 + lr) * 64;
    kf0[s] = load_frag(krow, lg * 8);
    kf1[s] = load_frag(krow, 64 + lg * 8);
  }

  const char* qbase = reinterpret_cast<const char*>(qT) + ((size_t)b * NPIX + jstart) * 128;
  const char* vbase = reinterpret_cast<const char*>(vC) + (size_t)b * 64 * 8192
                      + (size_t)jstart * 2;

  const int vo0_row = (t * 16) >> 7,        vo0_col = (t * 16) & 127;
  const int vo1_row = (4096 + t * 16) >> 7, vo1_col = (4096 + t * 16) & 127;

  f32x4 acc[4][4];
  #pragma unroll
  for (int m = 0; m < 4; ++m)
    #pragma unroll
    for (int s = 0; s < 4; ++s) acc[m][s] = (f32x4){0.f, 0.f, 0.f, 0.f};

  uint4 q0 = *reinterpret_cast<const uint4*>(qbase + t * 16);
  uint4 q1 = *reinterpret_cast<const uint4*>(qbase + 4096 + t * 16);
  uint4 v0 = *reinterpret_cast<const uint4*>(vbase + (size_t)vo0_row * 8192 + vo0_col);
  uint4 v1 = *reinterpret_cast<const uint4*>(vbase + (size_t)vo1_row * 8192 + vo1_col);

  for (int tile = 0; tile < ntiles; ++tile) {
    char* Qt = sQ + (tile & 1) * 8192;
    char* Vt = sV + (tile & 1) * 8192;
    stage_write(Qt, t, q0, q1);
    stage_write(Vt, t, v0, v1);
    __syncthreads();
    if (tile + 1 < ntiles) {
      const char* qsrc = qbase + (size_t)(tile + 1) * 8192;
      q0 = *reinterpret_cast<const uint4*>(qsrc + t * 16);
      q1 = *reinterpret_cast<const uint4*>(qsrc + 4096 + t * 16);
      const int jb = (tile + 1) * 128;
      v0 = *reinterpret_cast<const uint4*>(vbase + (size_t)vo0_row * 8192 + jb + vo0_col);
      v1 = *reinterpret_cast<const uint4*>(vbase + (size_t)vo1_row * 8192 + jb + vo1_col);
    }

    bf16x8 qf0[4], qf1[4], vf0[4], vf1[4];
    #pragma unroll
    for (int f = 0; f < 4; ++f) {
      qf0[f] = lds_frag(Qt, f * 16 + lr, lg * 8);
      qf1[f] = lds_frag(Qt, f * 16 + lr, 64 + lg * 8);
    }
    #pragma unroll
    for (int m = 0; m < 4; ++m) {
      vf0[m] = lds_frag(Vt, m * 16 + lr, lg * 8);
      vf1[m] = lds_frag(Vt, m * 16 + lr, 64 + lg * 8);
    }

    #pragma unroll
    for (int s = 0; s < 4; ++s) {
      f32x4 sj[4];
      #pragma unroll
      for (int f = 0; f < 4; ++f) {
        sj[f] = (f32x4){0.f, 0.f, 0.f, 0.f};
        sj[f] = __builtin_amdgcn_mfma_f32_16x16x32_bf16(qf0[f], kf0[s], sj[f], 0, 0, 0);
        sj[f] = __builtin_amdgcn_mfma_f32_16x16x32_bf16(qf1[f], kf1[s], sj[f], 0, 0, 0);
      }
      FragU pe0, pe1;
      #pragma unroll
      for (int r = 0; r < 4; ++r) {
        pe0.s[r]     = f2bf(__expf(sj[0][r]));
        pe0.s[4 + r] = f2bf(__expf(sj[1][r]));
        pe1.s[r]     = f2bf(__expf(sj[2][r]));
        pe1.s[4 + r] = f2bf(__expf(sj[3][r]));
      }
      #pragma unroll
      for (int m = 0; m < 4; ++m) {
        acc[m][s] = __builtin_amdgcn_mfma_f32_16x16x32_bf16(vf0[m], pe0.f, acc[m][s], 0, 0, 0);
        acc[m][s] = __builtin_amdgcn_mfma_f32_16x16x32_bf16(vf1[m], pe1.f, acc[m][s], 0, 0, 0);
      }
    }
    __syncthreads();
  }

  float* rbase = resP + ((size_t)part * 8 + b) * 64 * NPIX;
  #pragma unroll
  for (int m = 0; m < 4; ++m) {
    #pragma unroll
    for (int s = 0; s < 4; ++s) {
      #pragma unroll
      for (int r = 0; r < 4; ++r) {
        rbase[(size_t)(m * 16 + lg * 4 + r) * NPIX + i0 + s * 16 + lr] = acc[m][s][r];
      }
    }
  }
}

// ---------------------------------------------------------------------------
// Kernel 3.5: res = sum_p resP.  Streaming float4; 524288 threads, 1 each.
// ---------------------------------------------------------------------------
__global__ __launch_bounds__(256) void resred(
    const float* __restrict__ resP, float* __restrict__ res, int nparts)
{
  const size_t idx = (size_t)blockIdx.x * 256 + threadIdx.x;   // float4 index
  const float4* src = reinterpret_cast<const float4*>(resP) + idx;
  float4 a = src[0];
  for (int p = 1; p < nparts; ++p) {
    float4 b = src[(size_t)p * 524288];
    a.x += b.x; a.y += b.y; a.z += b.z; a.w += b.w;
  }
  reinterpret_cast<float4*>(res)[idx] = a;
}

// ---------------------------------------------------------------------------
// Kernel 4: out = Wo*res + bo + res.  Round-2 structure (verified, never hot):
// grid (16,8,4) x 256 threads, 16 outputs/thread, reload-residual.
// ---------------------------------------------------------------------------
__global__ __launch_bounds__(256) void out_proj(
    const float* __restrict__ res, const float* __restrict__ Wo,
    const float* __restrict__ bo, float* __restrict__ out)
{
  const int t  = threadIdx.x;
  const int b  = blockIdx.y;
  const int n  = blockIdx.x * 256 + t;
  const int o0 = blockIdx.z * 16;

  float rv[64];
  #pragma unroll
  for (int c = 0; c < 64; ++c) rv[c] = res[((size_t)b * 64 + c) * NPIX + n];

  #pragma unroll
  for (int oo = 0; oo < 16; ++oo) {
    float acc = bo[o0 + oo];
    #pragma unroll
    for (int c = 0; c < 64; ++c) acc += Wo[(o0 + oo) * 64 + c] * rv[c];
    acc += res[((size_t)b * 64 + o0 + oo) * NPIX + n];
    out[((size_t)b * 64 + o0 + oo) * NPIX + n] = acc;
  }
}

// ---------------------------------------------------------------------------
extern "C" void kernel_launch(void* const* d_in, const int* in_sizes, int n_in,
                              void* d_out, int out_size, void* d_ws, size_t ws_size,
                              hipStream_t stream) {
  const float* x  = (const float*)d_in[0];
  const float* Wq = (const float*)d_in[1];
  const float* bq = (const float*)d_in[2];
  const float* Wk = (const float*)d_in[3];
  const float* bk = (const float*)d_in[4];
  const float* Wv = (const float*)d_in[5];
  const float* bv = (const float*)d_in[6];
  const float* Wo = (const float*)d_in[7];
  const float* bo = (const float*)d_in[8];
  float* out = (float*)d_out;

  char* ws = (char*)d_ws;
  // res (8 MB) aliases qT+kT: written by resred only after attn_pv is done
  // with qT/kT/vC, and read only by out_proj.
  unsigned short* qT = (unsigned short*)(ws);                          // 4 MB
  unsigned short* kT = (unsigned short*)(ws + ((size_t)4 << 20));      // 4 MB
  float* res         = (float*)(ws);                                   // 8 MB (alias)
  unsigned short* vC = (unsigned short*)(ws + ((size_t)8 << 20));      // 4 MB
  float* Zpart       = (float*)(ws + ((size_t)12 << 20));              // <=512 KB
  float* resP        = (float*)(ws + ((size_t)13 << 20));              // nparts*8 MB

  int nparts;
  const size_t MB = (size_t)1 << 20;
  if      (ws_size >= 13 * MB + 4 * 8 * MB) nparts = 4;
  else if (ws_size >= 13 * MB + 2 * 8 * MB) nparts = 2;
  else                                      nparts = 1;
  const int ntiles = 64 / nparts;

  qkv_proj<<<dim3(16, 8, 4), 256, 0, stream>>>(x, Wq, bq, Wk, bk, Wv, bv, qT, kT, vC);
  attn_rowsum<<<dim3(16, 8, nparts), 256, 0, stream>>>(qT, kT, Zpart, ntiles);
  vscale<<<dim3(1024), 256, 0, stream>>>(vC, Zpart, nparts);
  attn_pv<<<dim3(16, 8, nparts), 256, 0, stream>>>(qT, kT, vC, resP, ntiles);
  resred<<<dim3(2048), 256, 0, stream>>>(resP, res, nparts);
  out_proj<<<dim3(16, 8, 4), 256, 0, stream>>>(res, Wo, bo, out);
}

// Round 7
// 227.015 us; speedup vs baseline: 3.5684x; 1.0010x over previous
//
#include <hip/hip_runtime.h>
#include <stdint.h>

#define NPIX 4096

typedef __bf16 bf16x8 __attribute__((ext_vector_type(8)));
typedef float  f32x4  __attribute__((ext_vector_type(4)));
typedef unsigned long long ull;

union FragU {
  bf16x8 f;
  uint4  u;
  ull    q[2];
  unsigned short s[8];
};

static __device__ __forceinline__ unsigned short f2bf(float x) {
  unsigned int u = __float_as_uint(x);
  u += 0x7FFFu + ((u >> 16) & 1u);
  return (unsigned short)(u >> 16);
}
static __device__ __forceinline__ float bf2f(unsigned short s) {
  return __uint_as_float(((unsigned int)s) << 16);
}
static __device__ __forceinline__ unsigned int pack2(unsigned short a, unsigned short b) {
  return (unsigned int)a | ((unsigned int)b << 16);
}

// Global-memory fragment load (16x16x32 A/B layout: 8B at byteOff, 8B at +32).
// VERIFIED layout (rounds 1-2-5-6, absmax 0.5).
static __device__ __forceinline__ bf16x8 load_frag(const unsigned short* base, int byteOff) {
  const char* p = reinterpret_cast<const char*>(base) + byteOff;
  uint2 a = *reinterpret_cast<const uint2*>(p);
  uint2 b = *reinterpret_cast<const uint2*>(p + 32);
  FragU fu;
  fu.u = make_uint4(a.x, a.y, b.x, b.y);
  return fu.f;
}

// LDS fragment load from a 64x64-short tile, row-major 128B rows,
// byte-swizzle L = P ^ ((row&7)<<4).  VERIFIED (rounds 2, 5, 6).
static __device__ __forceinline__ bf16x8 lds_frag(const char* base, int row, int cb) {
  const int swz = (row & 7) << 4;
  const int rb  = row << 7;
  ull a = *reinterpret_cast<const ull*>(base + (rb | (cb ^ swz)));
  ull b = *reinterpret_cast<const ull*>(base + (rb | ((cb + 32) ^ swz)));
  FragU fu;
  fu.q[0] = a; fu.q[1] = b;
  return fu.f;
}

// Thread t stages linear tile bytes [t*16, +16) and [4096+t*16, +16). VERIFIED.
static __device__ __forceinline__ void stage_write(char* dst, int t, uint4 r0, uint4 r1) {
  const int o0 = t * 16;
  const int o1 = 4096 + t * 16;
  *reinterpret_cast<uint4*>(dst + (o0 ^ (((o0 >> 7) & 7) << 4))) = r0;
  *reinterpret_cast<uint4*>(dst + (o1 ^ (((o1 >> 7) & 7) << 4))) = r1;
}

// ---------------------------------------------------------------------------
// Kernel 1: q,k,v = 1x1 conv.  qT,kT stored (B,N,64) bf16; v stored (B,64,N).
// VERBATIM rounds 2-6 (verified).
// ---------------------------------------------------------------------------
__global__ __launch_bounds__(256) void qkv_proj(
    const float* __restrict__ x,
    const float* __restrict__ Wq, const float* __restrict__ bq,
    const float* __restrict__ Wk, const float* __restrict__ bk,
    const float* __restrict__ Wv, const float* __restrict__ bv,
    unsigned short* __restrict__ qT, unsigned short* __restrict__ kT,
    unsigned short* __restrict__ vC)
{
  const int t  = threadIdx.x;
  const int b  = blockIdx.y;
  const int n  = blockIdx.x * 256 + t;
  const int o0 = blockIdx.z * 16;

  float xv[64];
  #pragma unroll
  for (int c = 0; c < 64; ++c) xv[c] = x[((size_t)b * 64 + c) * NPIX + n];

  const float* Wp[3] = {Wq, Wk, Wv};
  const float* Bp[3] = {bq, bk, bv};

  #pragma unroll
  for (int p = 0; p < 3; ++p) {
    const float* W  = Wp[p];
    const float* Bv = Bp[p];
    unsigned short outv[16];
    #pragma unroll
    for (int oo = 0; oo < 16; ++oo) {
      float acc = Bv[o0 + oo];
      #pragma unroll
      for (int c = 0; c < 64; ++c) acc += W[(o0 + oo) * 64 + c] * xv[c];
      outv[oo] = f2bf(acc);
    }
    if (p < 2) {
      unsigned short* dst = (p == 0 ? qT : kT) + ((size_t)b * NPIX + n) * 64 + o0;
      uint4 w0 = make_uint4(pack2(outv[0], outv[1]),  pack2(outv[2], outv[3]),
                            pack2(outv[4], outv[5]),  pack2(outv[6], outv[7]));
      uint4 w1 = make_uint4(pack2(outv[8], outv[9]),  pack2(outv[10], outv[11]),
                            pack2(outv[12], outv[13]), pack2(outv[14], outv[15]));
      *reinterpret_cast<uint4*>(dst)     = w0;
      *reinterpret_cast<uint4*>(dst + 8) = w1;
    } else {
      #pragma unroll
      for (int oo = 0; oo < 16; ++oo)
        vC[((size_t)b * 64 + o0 + oo) * NPIX + n] = outv[oo];
    }
  }
}

// ---------------------------------------------------------------------------
// Kernel 2: Zpart[part][b][j] = sum over this part's i of exp(q_j . k_i).
// VERBATIM rounds 5-6 (verified).
// ---------------------------------------------------------------------------
__global__ __launch_bounds__(256, 2) void attn_rowsum(
    const unsigned short* __restrict__ qT, const unsigned short* __restrict__ kT,
    float* __restrict__ Zpart, int ntiles)
{
  __shared__ __align__(16) char sK[2 * 8192];

  const int t    = threadIdx.x;
  const int b    = blockIdx.y;
  const int part = blockIdx.z;
  const int lane = t & 63;
  const int wv   = t >> 6;
  const int j0   = blockIdx.x * 256 + wv * 64;
  const int lr   = lane & 15;
  const int lg   = lane >> 4;

  bf16x8 aq0[4], aq1[4];
  #pragma unroll
  for (int f = 0; f < 4; ++f) {
    const unsigned short* qrow = qT + ((size_t)b * NPIX + j0 + f * 16 + lr) * 64;
    aq0[f] = load_frag(qrow, lg * 8);
    aq1[f] = load_frag(qrow, 64 + lg * 8);
  }

  const char* kbase = reinterpret_cast<const char*>(kT) + (size_t)b * NPIX * 128
                      + (size_t)part * ntiles * 8192;

  float zacc[4][4];
  #pragma unroll
  for (int f = 0; f < 4; ++f)
    #pragma unroll
    for (int r = 0; r < 4; ++r) zacc[f][r] = 0.f;

  uint4 r0 = *reinterpret_cast<const uint4*>(kbase + t * 16);
  uint4 r1 = *reinterpret_cast<const uint4*>(kbase + 4096 + t * 16);

  for (int tile = 0; tile < ntiles; ++tile) {
    char* buf = sK + (tile & 1) * 8192;
    stage_write(buf, t, r0, r1);
    __syncthreads();
    if (tile + 1 < ntiles) {
      const char* src = kbase + (size_t)(tile + 1) * 8192;
      r0 = *reinterpret_cast<const uint4*>(src + t * 16);
      r1 = *reinterpret_cast<const uint4*>(src + 4096 + t * 16);
    }
    bf16x8 kf0[4], kf1[4];
    #pragma unroll
    for (int s = 0; s < 4; ++s) {
      kf0[s] = lds_frag(buf, s * 16 + lr, lg * 8);
      kf1[s] = lds_frag(buf, s * 16 + lr, 64 + lg * 8);
    }
    #pragma unroll
    for (int f = 0; f < 4; ++f) {
      #pragma unroll
      for (int s = 0; s < 4; ++s) {
        f32x4 S = {0.f, 0.f, 0.f, 0.f};
        S = __builtin_amdgcn_mfma_f32_16x16x32_bf16(aq0[f], kf0[s], S, 0, 0, 0);
        S = __builtin_amdgcn_mfma_f32_16x16x32_bf16(aq1[f], kf1[s], S, 0, 0, 0);
        zacc[f][0] += __expf(S[0]);
        zacc[f][1] += __expf(S[1]);
        zacc[f][2] += __expf(S[2]);
        zacc[f][3] += __expf(S[3]);
      }
    }
    __syncthreads();
  }

  #pragma unroll
  for (int f = 0; f < 4; ++f) {
    #pragma unroll
    for (int m = 8; m >= 1; m >>= 1) {
      #pragma unroll
      for (int r = 0; r < 4; ++r) zacc[f][r] += __shfl_xor(zacc[f][r], m, 64);
    }
  }
  if (lr == 0) {
    float* dst = Zpart + ((size_t)part * 8 + b) * NPIX + j0 + lg * 4;
    #pragma unroll
    for (int f = 0; f < 4; ++f) {
      #pragma unroll
      for (int r = 0; r < 4; ++r) dst[f * 16 + r] = zacc[f][r];
    }
  }
}

// ---------------------------------------------------------------------------
// Kernel 2.5 (fused zred+vscale): v'[c,n] = v[c,n] / sum_p Zpart[p][b][n].
// VERBATIM round 6 (verified).
// ---------------------------------------------------------------------------
__global__ __launch_bounds__(256) void vscale(
    unsigned short* __restrict__ vC, const float* __restrict__ Zpart, int nparts)
{
  const int idx = blockIdx.x * 256 + threadIdx.x;   // 0..262143
  const int jc  = idx & 511;
  const int b   = idx >> 15;
  unsigned short* p = vC + (size_t)idx * 8;
  const float* zb = Zpart + (size_t)b * NPIX + jc * 8;
  float z[8];
  #pragma unroll
  for (int e = 0; e < 8; ++e) z[e] = 0.f;
  for (int pp = 0; pp < nparts; ++pp) {
    const float* zp = zb + (size_t)pp * 8 * NPIX;
    #pragma unroll
    for (int e = 0; e < 8; ++e) z[e] += zp[e];
  }
  FragU v;
  v.q[0] = reinterpret_cast<const ull*>(p)[0];
  v.q[1] = reinterpret_cast<const ull*>(p)[1];
  #pragma unroll
  for (int e = 0; e < 8; ++e) v.s[e] = f2bf(bf2f(v.s[e]) * (1.0f / z[e]));
  reinterpret_cast<ull*>(p)[0] = v.q[0];
  reinterpret_cast<ull*>(p)[1] = v.q[1];
}

// ---------------------------------------------------------------------------
// Kernel 3: resP[part][b][c][i] = sum over part's j of exp(q_j.k_i)*v'[c,j].
// Round-6 structure; ONLY change: P packing via compiler bf16 casts
// ((__bf16)x = RNE fptrunc, numerically identical to f2bf; clang pairs them
// into v_cvt_pk_bf16_f32 — replaces ~320 bit-twiddle VALU insts/tile).
// ---------------------------------------------------------------------------
__global__ __launch_bounds__(256, 2) void attn_pv(
    const unsigned short* __restrict__ qT, const unsigned short* __restrict__ kT,
    const unsigned short* __restrict__ vC, float* __restrict__ resP, int ntiles)
{
  __shared__ __align__(16) char sQ[2 * 8192];
  __shared__ __align__(16) char sV[2 * 8192];

  const int t    = threadIdx.x;
  const int b    = blockIdx.y;
  const int part = blockIdx.z;
  const int lane = t & 63;
  const int wv   = t >> 6;
  const int i0   = blockIdx.x * 256 + wv * 64;
  const int lr   = lane & 15;
  const int lg   = lane >> 4;
  const int jstart = part * ntiles * 64;

  bf16x8 kf0[4], kf1[4];
  #pragma unroll
  for (int s = 0; s < 4; ++s) {
    const unsigned short* krow = kT + ((size_t)b * NPIX + i0 + s * 16 + lr) * 64;
    kf0[s] = load_frag(krow, lg * 8);
    kf1[s] = load_frag(krow, 64 + lg * 8);
  }

  const char* qbase = reinterpret_cast<const char*>(qT) + ((size_t)b * NPIX + jstart) * 128;
  const char* vbase = reinterpret_cast<const char*>(vC) + (size_t)b * 64 * 8192
                      + (size_t)jstart * 2;

  const int vo0_row = (t * 16) >> 7,        vo0_col = (t * 16) & 127;
  const int vo1_row = (4096 + t * 16) >> 7, vo1_col = (4096 + t * 16) & 127;

  f32x4 acc[4][4];
  #pragma unroll
  for (int m = 0; m < 4; ++m)
    #pragma unroll
    for (int s = 0; s < 4; ++s) acc[m][s] = (f32x4){0.f, 0.f, 0.f, 0.f};

  uint4 q0 = *reinterpret_cast<const uint4*>(qbase + t * 16);
  uint4 q1 = *reinterpret_cast<const uint4*>(qbase + 4096 + t * 16);
  uint4 v0 = *reinterpret_cast<const uint4*>(vbase + (size_t)vo0_row * 8192 + vo0_col);
  uint4 v1 = *reinterpret_cast<const uint4*>(vbase + (size_t)vo1_row * 8192 + vo1_col);

  for (int tile = 0; tile < ntiles; ++tile) {
    char* Qt = sQ + (tile & 1) * 8192;
    char* Vt = sV + (tile & 1) * 8192;
    stage_write(Qt, t, q0, q1);
    stage_write(Vt, t, v0, v1);
    __syncthreads();
    if (tile + 1 < ntiles) {
      const char* qsrc = qbase + (size_t)(tile + 1) * 8192;
      q0 = *reinterpret_cast<const uint4*>(qsrc + t * 16);
      q1 = *reinterpret_cast<const uint4*>(qsrc + 4096 + t * 16);
      const int jb = (tile + 1) * 128;
      v0 = *reinterpret_cast<const uint4*>(vbase + (size_t)vo0_row * 8192 + jb + vo0_col);
      v1 = *reinterpret_cast<const uint4*>(vbase + (size_t)vo1_row * 8192 + jb + vo1_col);
    }

    bf16x8 qf0[4], qf1[4], vf0[4], vf1[4];
    #pragma unroll
    for (int f = 0; f < 4; ++f) {
      qf0[f] = lds_frag(Qt, f * 16 + lr, lg * 8);
      qf1[f] = lds_frag(Qt, f * 16 + lr, 64 + lg * 8);
    }
    #pragma unroll
    for (int m = 0; m < 4; ++m) {
      vf0[m] = lds_frag(Vt, m * 16 + lr, lg * 8);
      vf1[m] = lds_frag(Vt, m * 16 + lr, 64 + lg * 8);
    }

    #pragma unroll
    for (int s = 0; s < 4; ++s) {
      f32x4 sj[4];
      #pragma unroll
      for (int f = 0; f < 4; ++f) {
        sj[f] = (f32x4){0.f, 0.f, 0.f, 0.f};
        sj[f] = __builtin_amdgcn_mfma_f32_16x16x32_bf16(qf0[f], kf0[s], sj[f], 0, 0, 0);
        sj[f] = __builtin_amdgcn_mfma_f32_16x16x32_bf16(qf1[f], kf1[s], sj[f], 0, 0, 0);
      }
      FragU pe0, pe1;
      #pragma unroll
      for (int r = 0; r < 4; ++r) {
        pe0.f[r]     = (__bf16)__expf(sj[0][r]);
        pe0.f[4 + r] = (__bf16)__expf(sj[1][r]);
        pe1.f[r]     = (__bf16)__expf(sj[2][r]);
        pe1.f[4 + r] = (__bf16)__expf(sj[3][r]);
      }
      #pragma unroll
      for (int m = 0; m < 4; ++m) {
        acc[m][s] = __builtin_amdgcn_mfma_f32_16x16x32_bf16(vf0[m], pe0.f, acc[m][s], 0, 0, 0);
        acc[m][s] = __builtin_amdgcn_mfma_f32_16x16x32_bf16(vf1[m], pe1.f, acc[m][s], 0, 0, 0);
      }
    }
    __syncthreads();
  }

  float* rbase = resP + ((size_t)part * 8 + b) * 64 * NPIX;
  #pragma unroll
  for (int m = 0; m < 4; ++m) {
    #pragma unroll
    for (int s = 0; s < 4; ++s) {
      #pragma unroll
      for (int r = 0; r < 4; ++r) {
        rbase[(size_t)(m * 16 + lg * 4 + r) * NPIX + i0 + s * 16 + lr] = acc[m][s][r];
      }
    }
  }
}

// ---------------------------------------------------------------------------
// Kernel 3.5: res = sum_p resP.  VERBATIM round 6 (verified).
// ---------------------------------------------------------------------------
__global__ __launch_bounds__(256) void resred(
    const float* __restrict__ resP, float* __restrict__ res, int nparts)
{
  const size_t idx = (size_t)blockIdx.x * 256 + threadIdx.x;   // float4 index
  const float4* src = reinterpret_cast<const float4*>(resP) + idx;
  float4 a = src[0];
  for (int p = 1; p < nparts; ++p) {
    float4 b = src[(size_t)p * 524288];
    a.x += b.x; a.y += b.y; a.z += b.z; a.w += b.w;
  }
  reinterpret_cast<float4*>(res)[idx] = a;
}

// ---------------------------------------------------------------------------
// Kernel 4: out = Wo*res + bo + res.  VERBATIM round 6 (verified).
// ---------------------------------------------------------------------------
__global__ __launch_bounds__(256) void out_proj(
    const float* __restrict__ res, const float* __restrict__ Wo,
    const float* __restrict__ bo, float* __restrict__ out)
{
  const int t  = threadIdx.x;
  const int b  = blockIdx.y;
  const int n  = blockIdx.x * 256 + t;
  const int o0 = blockIdx.z * 16;

  float rv[64];
  #pragma unroll
  for (int c = 0; c < 64; ++c) rv[c] = res[((size_t)b * 64 + c) * NPIX + n];

  #pragma unroll
  for (int oo = 0; oo < 16; ++oo) {
    float acc = bo[o0 + oo];
    #pragma unroll
    for (int c = 0; c < 64; ++c) acc += Wo[(o0 + oo) * 64 + c] * rv[c];
    acc += res[((size_t)b * 64 + o0 + oo) * NPIX + n];
    out[((size_t)b * 64 + o0 + oo) * NPIX + n] = acc;
  }
}

// ---------------------------------------------------------------------------
extern "C" void kernel_launch(void* const* d_in, const int* in_sizes, int n_in,
                              void* d_out, int out_size, void* d_ws, size_t ws_size,
                              hipStream_t stream) {
  const float* x  = (const float*)d_in[0];
  const float* Wq = (const float*)d_in[1];
  const float* bq = (const float*)d_in[2];
  const float* Wk = (const float*)d_in[3];
  const float* bk = (const float*)d_in[4];
  const float* Wv = (const float*)d_in[5];
  const float* bv = (const float*)d_in[6];
  const float* Wo = (const float*)d_in[7];
  const float* bo = (const float*)d_in[8];
  float* out = (float*)d_out;

  char* ws = (char*)d_ws;
  // res (8 MB) aliases qT+kT: written by resred only after attn_pv is done
  // with qT/kT/vC, and read only by out_proj.
  unsigned short* qT = (unsigned short*)(ws);                          // 4 MB
  unsigned short* kT = (unsigned short*)(ws + ((size_t)4 << 20));      // 4 MB
  float* res         = (float*)(ws);                                   // 8 MB (alias)
  unsigned short* vC = (unsigned short*)(ws + ((size_t)8 << 20));      // 4 MB
  float* Zpart       = (float*)(ws + ((size_t)12 << 20));              // <=1 MB (nparts<=8)
  float* resP        = (float*)(ws + ((size_t)13 << 20));              // nparts*8 MB

  int nparts;
  const size_t MB = (size_t)1 << 20;
  if      (ws_size >= 13 * MB + 8 * 8 * MB) nparts = 8;   // grid 1024 -> 4 blocks/CU
  else if (ws_size >= 13 * MB + 4 * 8 * MB) nparts = 4;
  else if (ws_size >= 13 * MB + 2 * 8 * MB) nparts = 2;
  else                                      nparts = 1;
  const int ntiles = 64 / nparts;

  qkv_proj<<<dim3(16, 8, 4), 256, 0, stream>>>(x, Wq, bq, Wk, bk, Wv, bv, qT, kT, vC);
  attn_rowsum<<<dim3(16, 8, nparts), 256, 0, stream>>>(qT, kT, Zpart, ntiles);
  vscale<<<dim3(1024), 256, 0, stream>>>(vC, Zpart, nparts);
  attn_pv<<<dim3(16, 8, nparts), 256, 0, stream>>>(qT, kT, vC, resP, ntiles);
  resred<<<dim3(2048), 256, 0, stream>>>(resP, res, nparts);
  out_proj<<<dim3(16, 8, 4), 256, 0, stream>>>(res, Wo, bo, out);
}

// Round 8
// 216.432 us; speedup vs baseline: 3.7428x; 1.0489x over previous
//
#include <hip/hip_runtime.h>
#include <stdint.h>

#define NPIX 4096
#define LOG2E 1.44269504088896340736f

typedef __bf16 bf16x8 __attribute__((ext_vector_type(8)));
typedef float  f32x4  __attribute__((ext_vector_type(4)));
typedef unsigned long long ull;

union FragU {
  bf16x8 f;
  uint4  u;
  ull    q[2];
  unsigned short s[8];
};

static __device__ __forceinline__ unsigned short f2bf(float x) {
  unsigned int u = __float_as_uint(x);
  u += 0x7FFFu + ((u >> 16) & 1u);
  return (unsigned short)(u >> 16);
}
static __device__ __forceinline__ float bf2f(unsigned short s) {
  return __uint_as_float(((unsigned int)s) << 16);
}
static __device__ __forceinline__ unsigned int pack2(unsigned short a, unsigned short b) {
  return (unsigned int)a | ((unsigned int)b << 16);
}
static __device__ __forceinline__ float e2(float x) { return __builtin_amdgcn_exp2f(x); }

// Global-memory fragment load (16x16x32 A/B layout: 8B at byteOff, 8B at +32).
// VERIFIED layout (rounds 1-2-5-6-7, absmax 0.5).
static __device__ __forceinline__ bf16x8 load_frag(const unsigned short* base, int byteOff) {
  const char* p = reinterpret_cast<const char*>(base) + byteOff;
  uint2 a = *reinterpret_cast<const uint2*>(p);
  uint2 b = *reinterpret_cast<const uint2*>(p + 32);
  FragU fu;
  fu.u = make_uint4(a.x, a.y, b.x, b.y);
  return fu.f;
}

// ROTATION swizzle (replaces XOR): byte col' = (col + 16*(row&7)) & 127.
// Bank-uniform for the 8B fragment reads (exactly 4 touches/bank per
// ds_read_b64) AND bijective per row for the 16B staged writes. Applied
// identically on write (stage_write) and read (lds_frag) -> correctness is
// structural. 8B/16B chunks are 8-aligned and never cross the &127 wrap.
static __device__ __forceinline__ int rotc(int row, int col) {
  return (col + ((row & 7) << 4)) & 127;
}

// LDS fragment load from a 64x64-short tile, row-major 128B rows, rotated.
static __device__ __forceinline__ bf16x8 lds_frag(const char* base, int row, int cb) {
  const int rb = row << 7;
  ull a = *reinterpret_cast<const ull*>(base + rb + rotc(row, cb));
  ull b = *reinterpret_cast<const ull*>(base + rb + rotc(row, cb + 32));
  FragU fu;
  fu.q[0] = a; fu.q[1] = b;
  return fu.f;
}

// Thread t stages linear tile bytes [t*16, +16) and [4096+t*16, +16), rotated.
static __device__ __forceinline__ void stage_write(char* dst, int t, uint4 r0, uint4 r1) {
  const int o0 = t * 16;
  const int o1 = 4096 + t * 16;
  const int w0 = o0 >> 7, w1 = o1 >> 7;
  *reinterpret_cast<uint4*>(dst + (w0 << 7) + rotc(w0, o0 & 127)) = r0;
  *reinterpret_cast<uint4*>(dst + (w1 << 7) + rotc(w1, o1 & 127)) = r1;
}

// ---------------------------------------------------------------------------
// Kernel 1: q,k,v = 1x1 conv.  qT,kT stored (B,N,64) bf16; v stored (B,64,N).
// ONLY change vs rounds 2-7: q scaled by LOG2E (so attn uses exp2 directly).
// ---------------------------------------------------------------------------
__global__ __launch_bounds__(256) void qkv_proj(
    const float* __restrict__ x,
    const float* __restrict__ Wq, const float* __restrict__ bq,
    const float* __restrict__ Wk, const float* __restrict__ bk,
    const float* __restrict__ Wv, const float* __restrict__ bv,
    unsigned short* __restrict__ qT, unsigned short* __restrict__ kT,
    unsigned short* __restrict__ vC)
{
  const int t  = threadIdx.x;
  const int b  = blockIdx.y;
  const int n  = blockIdx.x * 256 + t;
  const int o0 = blockIdx.z * 16;

  float xv[64];
  #pragma unroll
  for (int c = 0; c < 64; ++c) xv[c] = x[((size_t)b * 64 + c) * NPIX + n];

  const float* Wp[3] = {Wq, Wk, Wv};
  const float* Bp[3] = {bq, bk, bv};

  #pragma unroll
  for (int p = 0; p < 3; ++p) {
    const float* W  = Wp[p];
    const float* Bv = Bp[p];
    unsigned short outv[16];
    #pragma unroll
    for (int oo = 0; oo < 16; ++oo) {
      float acc = Bv[o0 + oo];
      #pragma unroll
      for (int c = 0; c < 64; ++c) acc += W[(o0 + oo) * 64 + c] * xv[c];
      if (p == 0) acc *= LOG2E;      // exp(q.k) == exp2((q*log2e).k)
      outv[oo] = f2bf(acc);
    }
    if (p < 2) {
      unsigned short* dst = (p == 0 ? qT : kT) + ((size_t)b * NPIX + n) * 64 + o0;
      uint4 w0 = make_uint4(pack2(outv[0], outv[1]),  pack2(outv[2], outv[3]),
                            pack2(outv[4], outv[5]),  pack2(outv[6], outv[7]));
      uint4 w1 = make_uint4(pack2(outv[8], outv[9]),  pack2(outv[10], outv[11]),
                            pack2(outv[12], outv[13]), pack2(outv[14], outv[15]));
      *reinterpret_cast<uint4*>(dst)     = w0;
      *reinterpret_cast<uint4*>(dst + 8) = w1;
    } else {
      #pragma unroll
      for (int oo = 0; oo < 16; ++oo)
        vC[((size_t)b * 64 + o0 + oo) * NPIX + n] = outv[oo];
    }
  }
}

// ---------------------------------------------------------------------------
// Kernel 2: Zpart[part][b][j] = sum over this part's i of 2^(q'_j . k_i).
// Rounds 5-7 structure; rotation swizzle + exp2.
// ---------------------------------------------------------------------------
__global__ __launch_bounds__(256, 2) void attn_rowsum(
    const unsigned short* __restrict__ qT, const unsigned short* __restrict__ kT,
    float* __restrict__ Zpart, int ntiles)
{
  __shared__ __align__(16) char sK[2 * 8192];

  const int t    = threadIdx.x;
  const int b    = blockIdx.y;
  const int part = blockIdx.z;
  const int lane = t & 63;
  const int wv   = t >> 6;
  const int j0   = blockIdx.x * 256 + wv * 64;
  const int lr   = lane & 15;
  const int lg   = lane >> 4;

  bf16x8 aq0[4], aq1[4];
  #pragma unroll
  for (int f = 0; f < 4; ++f) {
    const unsigned short* qrow = qT + ((size_t)b * NPIX + j0 + f * 16 + lr) * 64;
    aq0[f] = load_frag(qrow, lg * 8);
    aq1[f] = load_frag(qrow, 64 + lg * 8);
  }

  const char* kbase = reinterpret_cast<const char*>(kT) + (size_t)b * NPIX * 128
                      + (size_t)part * ntiles * 8192;

  float zacc[4][4];
  #pragma unroll
  for (int f = 0; f < 4; ++f)
    #pragma unroll
    for (int r = 0; r < 4; ++r) zacc[f][r] = 0.f;

  uint4 r0 = *reinterpret_cast<const uint4*>(kbase + t * 16);
  uint4 r1 = *reinterpret_cast<const uint4*>(kbase + 4096 + t * 16);

  for (int tile = 0; tile < ntiles; ++tile) {
    char* buf = sK + (tile & 1) * 8192;
    stage_write(buf, t, r0, r1);
    __syncthreads();
    if (tile + 1 < ntiles) {
      const char* src = kbase + (size_t)(tile + 1) * 8192;
      r0 = *reinterpret_cast<const uint4*>(src + t * 16);
      r1 = *reinterpret_cast<const uint4*>(src + 4096 + t * 16);
    }
    bf16x8 kf0[4], kf1[4];
    #pragma unroll
    for (int s = 0; s < 4; ++s) {
      kf0[s] = lds_frag(buf, s * 16 + lr, lg * 8);
      kf1[s] = lds_frag(buf, s * 16 + lr, 64 + lg * 8);
    }
    #pragma unroll
    for (int f = 0; f < 4; ++f) {
      #pragma unroll
      for (int s = 0; s < 4; ++s) {
        f32x4 S = {0.f, 0.f, 0.f, 0.f};
        S = __builtin_amdgcn_mfma_f32_16x16x32_bf16(aq0[f], kf0[s], S, 0, 0, 0);
        S = __builtin_amdgcn_mfma_f32_16x16x32_bf16(aq1[f], kf1[s], S, 0, 0, 0);
        zacc[f][0] += e2(S[0]);
        zacc[f][1] += e2(S[1]);
        zacc[f][2] += e2(S[2]);
        zacc[f][3] += e2(S[3]);
      }
    }
    __syncthreads();
  }

  #pragma unroll
  for (int f = 0; f < 4; ++f) {
    #pragma unroll
    for (int m = 8; m >= 1; m >>= 1) {
      #pragma unroll
      for (int r = 0; r < 4; ++r) zacc[f][r] += __shfl_xor(zacc[f][r], m, 64);
    }
  }
  if (lr == 0) {
    float* dst = Zpart + ((size_t)part * 8 + b) * NPIX + j0 + lg * 4;
    #pragma unroll
    for (int f = 0; f < 4; ++f) {
      #pragma unroll
      for (int r = 0; r < 4; ++r) dst[f * 16 + r] = zacc[f][r];
    }
  }
}

// ---------------------------------------------------------------------------
// Kernel 2.5 (fused zred+vscale): v'[c,n] = v[c,n] / sum_p Zpart[p][b][n].
// VERBATIM rounds 6-7 (verified).
// ---------------------------------------------------------------------------
__global__ __launch_bounds__(256) void vscale(
    unsigned short* __restrict__ vC, const float* __restrict__ Zpart, int nparts)
{
  const int idx = blockIdx.x * 256 + threadIdx.x;   // 0..262143
  const int jc  = idx & 511;
  const int b   = idx >> 15;
  unsigned short* p = vC + (size_t)idx * 8;
  const float* zb = Zpart + (size_t)b * NPIX + jc * 8;
  float z[8];
  #pragma unroll
  for (int e = 0; e < 8; ++e) z[e] = 0.f;
  for (int pp = 0; pp < nparts; ++pp) {
    const float* zp = zb + (size_t)pp * 8 * NPIX;
    #pragma unroll
    for (int e = 0; e < 8; ++e) z[e] += zp[e];
  }
  FragU v;
  v.q[0] = reinterpret_cast<const ull*>(p)[0];
  v.q[1] = reinterpret_cast<const ull*>(p)[1];
  #pragma unroll
  for (int e = 0; e < 8; ++e) v.s[e] = f2bf(bf2f(v.s[e]) * (1.0f / z[e]));
  reinterpret_cast<ull*>(p)[0] = v.q[0];
  reinterpret_cast<ull*>(p)[1] = v.q[1];
}

// ---------------------------------------------------------------------------
// Kernel 3: resP[part][b][c][i] = sum over part's j of 2^(q'_j.k_i)*v'[c,j].
// Round-7 structure; rotation swizzle + exp2.
// ---------------------------------------------------------------------------
__global__ __launch_bounds__(256, 2) void attn_pv(
    const unsigned short* __restrict__ qT, const unsigned short* __restrict__ kT,
    const unsigned short* __restrict__ vC, float* __restrict__ resP, int ntiles)
{
  __shared__ __align__(16) char sQ[2 * 8192];
  __shared__ __align__(16) char sV[2 * 8192];

  const int t    = threadIdx.x;
  const int b    = blockIdx.y;
  const int part = blockIdx.z;
  const int lane = t & 63;
  const int wv   = t >> 6;
  const int i0   = blockIdx.x * 256 + wv * 64;
  const int lr   = lane & 15;
  const int lg   = lane >> 4;
  const int jstart = part * ntiles * 64;

  bf16x8 kf0[4], kf1[4];
  #pragma unroll
  for (int s = 0; s < 4; ++s) {
    const unsigned short* krow = kT + ((size_t)b * NPIX + i0 + s * 16 + lr) * 64;
    kf0[s] = load_frag(krow, lg * 8);
    kf1[s] = load_frag(krow, 64 + lg * 8);
  }

  const char* qbase = reinterpret_cast<const char*>(qT) + ((size_t)b * NPIX + jstart) * 128;
  const char* vbase = reinterpret_cast<const char*>(vC) + (size_t)b * 64 * 8192
                      + (size_t)jstart * 2;

  const int vo0_row = (t * 16) >> 7,        vo0_col = (t * 16) & 127;
  const int vo1_row = (4096 + t * 16) >> 7, vo1_col = (4096 + t * 16) & 127;

  f32x4 acc[4][4];
  #pragma unroll
  for (int m = 0; m < 4; ++m)
    #pragma unroll
    for (int s = 0; s < 4; ++s) acc[m][s] = (f32x4){0.f, 0.f, 0.f, 0.f};

  uint4 q0 = *reinterpret_cast<const uint4*>(qbase + t * 16);
  uint4 q1 = *reinterpret_cast<const uint4*>(qbase + 4096 + t * 16);
  uint4 v0 = *reinterpret_cast<const uint4*>(vbase + (size_t)vo0_row * 8192 + vo0_col);
  uint4 v1 = *reinterpret_cast<const uint4*>(vbase + (size_t)vo1_row * 8192 + vo1_col);

  for (int tile = 0; tile < ntiles; ++tile) {
    char* Qt = sQ + (tile & 1) * 8192;
    char* Vt = sV + (tile & 1) * 8192;
    stage_write(Qt, t, q0, q1);
    stage_write(Vt, t, v0, v1);
    __syncthreads();
    if (tile + 1 < ntiles) {
      const char* qsrc = qbase + (size_t)(tile + 1) * 8192;
      q0 = *reinterpret_cast<const uint4*>(qsrc + t * 16);
      q1 = *reinterpret_cast<const uint4*>(qsrc + 4096 + t * 16);
      const int jb = (tile + 1) * 128;
      v0 = *reinterpret_cast<const uint4*>(vbase + (size_t)vo0_row * 8192 + jb + vo0_col);
      v1 = *reinterpret_cast<const uint4*>(vbase + (size_t)vo1_row * 8192 + jb + vo1_col);
    }

    bf16x8 qf0[4], qf1[4], vf0[4], vf1[4];
    #pragma unroll
    for (int f = 0; f < 4; ++f) {
      qf0[f] = lds_frag(Qt, f * 16 + lr, lg * 8);
      qf1[f] = lds_frag(Qt, f * 16 + lr, 64 + lg * 8);
    }
    #pragma unroll
    for (int m = 0; m < 4; ++m) {
      vf0[m] = lds_frag(Vt, m * 16 + lr, lg * 8);
      vf1[m] = lds_frag(Vt, m * 16 + lr, 64 + lg * 8);
    }

    #pragma unroll
    for (int s = 0; s < 4; ++s) {
      f32x4 sj[4];
      #pragma unroll
      for (int f = 0; f < 4; ++f) {
        sj[f] = (f32x4){0.f, 0.f, 0.f, 0.f};
        sj[f] = __builtin_amdgcn_mfma_f32_16x16x32_bf16(qf0[f], kf0[s], sj[f], 0, 0, 0);
        sj[f] = __builtin_amdgcn_mfma_f32_16x16x32_bf16(qf1[f], kf1[s], sj[f], 0, 0, 0);
      }
      FragU pe0, pe1;
      #pragma unroll
      for (int r = 0; r < 4; ++r) {
        pe0.f[r]     = (__bf16)e2(sj[0][r]);
        pe0.f[4 + r] = (__bf16)e2(sj[1][r]);
        pe1.f[r]     = (__bf16)e2(sj[2][r]);
        pe1.f[4 + r] = (__bf16)e2(sj[3][r]);
      }
      #pragma unroll
      for (int m = 0; m < 4; ++m) {
        acc[m][s] = __builtin_amdgcn_mfma_f32_16x16x32_bf16(vf0[m], pe0.f, acc[m][s], 0, 0, 0);
        acc[m][s] = __builtin_amdgcn_mfma_f32_16x16x32_bf16(vf1[m], pe1.f, acc[m][s], 0, 0, 0);
      }
    }
    __syncthreads();
  }

  float* rbase = resP + ((size_t)part * 8 + b) * 64 * NPIX;
  #pragma unroll
  for (int m = 0; m < 4; ++m) {
    #pragma unroll
    for (int s = 0; s < 4; ++s) {
      #pragma unroll
      for (int r = 0; r < 4; ++r) {
        rbase[(size_t)(m * 16 + lg * 4 + r) * NPIX + i0 + s * 16 + lr] = acc[m][s][r];
      }
    }
  }
}

// ---------------------------------------------------------------------------
// Kernel 3.5: res = sum_p resP.  VERBATIM rounds 6-7 (verified).
// ---------------------------------------------------------------------------
__global__ __launch_bounds__(256) void resred(
    const float* __restrict__ resP, float* __restrict__ res, int nparts)
{
  const size_t idx = (size_t)blockIdx.x * 256 + threadIdx.x;   // float4 index
  const float4* src = reinterpret_cast<const float4*>(resP) + idx;
  float4 a = src[0];
  for (int p = 1; p < nparts; ++p) {
    float4 b = src[(size_t)p * 524288];
    a.x += b.x; a.y += b.y; a.z += b.z; a.w += b.w;
  }
  reinterpret_cast<float4*>(res)[idx] = a;
}

// ---------------------------------------------------------------------------
// Kernel 4: out = Wo*res + bo + res.  VERBATIM rounds 6-7 (verified).
// ---------------------------------------------------------------------------
__global__ __launch_bounds__(256) void out_proj(
    const float* __restrict__ res, const float* __restrict__ Wo,
    const float* __restrict__ bo, float* __restrict__ out)
{
  const int t  = threadIdx.x;
  const int b  = blockIdx.y;
  const int n  = blockIdx.x * 256 + t;
  const int o0 = blockIdx.z * 16;

  float rv[64];
  #pragma unroll
  for (int c = 0; c < 64; ++c) rv[c] = res[((size_t)b * 64 + c) * NPIX + n];

  #pragma unroll
  for (int oo = 0; oo < 16; ++oo) {
    float acc = bo[o0 + oo];
    #pragma unroll
    for (int c = 0; c < 64; ++c) acc += Wo[(o0 + oo) * 64 + c] * rv[c];
    acc += res[((size_t)b * 64 + o0 + oo) * NPIX + n];
    out[((size_t)b * 64 + o0 + oo) * NPIX + n] = acc;
  }
}

// ---------------------------------------------------------------------------
extern "C" void kernel_launch(void* const* d_in, const int* in_sizes, int n_in,
                              void* d_out, int out_size, void* d_ws, size_t ws_size,
                              hipStream_t stream) {
  const float* x  = (const float*)d_in[0];
  const float* Wq = (const float*)d_in[1];
  const float* bq = (const float*)d_in[2];
  const float* Wk = (const float*)d_in[3];
  const float* bk = (const float*)d_in[4];
  const float* Wv = (const float*)d_in[5];
  const float* bv = (const float*)d_in[6];
  const float* Wo = (const float*)d_in[7];
  const float* bo = (const float*)d_in[8];
  float* out = (float*)d_out;

  char* ws = (char*)d_ws;
  // res (8 MB) aliases qT+kT: written by resred only after attn_pv is done
  // with qT/kT/vC, and read only by out_proj.
  unsigned short* qT = (unsigned short*)(ws);                          // 4 MB
  unsigned short* kT = (unsigned short*)(ws + ((size_t)4 << 20));      // 4 MB
  float* res         = (float*)(ws);                                   // 8 MB (alias)
  unsigned short* vC = (unsigned short*)(ws + ((size_t)8 << 20));      // 4 MB
  float* Zpart       = (float*)(ws + ((size_t)12 << 20));              // <=1 MB (nparts<=8)
  float* resP        = (float*)(ws + ((size_t)13 << 20));              // nparts*8 MB

  int nparts;
  const size_t MB = (size_t)1 << 20;
  if      (ws_size >= 13 * MB + 8 * 8 * MB) nparts = 8;   // grid 1024 -> 4 blocks/CU
  else if (ws_size >= 13 * MB + 4 * 8 * MB) nparts = 4;
  else if (ws_size >= 13 * MB + 2 * 8 * MB) nparts = 2;
  else                                      nparts = 1;
  const int ntiles = 64 / nparts;

  qkv_proj<<<dim3(16, 8, 4), 256, 0, stream>>>(x, Wq, bq, Wk, bk, Wv, bv, qT, kT, vC);
  attn_rowsum<<<dim3(16, 8, nparts), 256, 0, stream>>>(qT, kT, Zpart, ntiles);
  vscale<<<dim3(1024), 256, 0, stream>>>(vC, Zpart, nparts);
  attn_pv<<<dim3(16, 8, nparts), 256, 0, stream>>>(qT, kT, vC, resP, ntiles);
  resred<<<dim3(2048), 256, 0, stream>>>(resP, res, nparts);
  out_proj<<<dim3(16, 8, 4), 256, 0, stream>>>(res, Wo, bo, out);
}

// Round 9
// 213.893 us; speedup vs baseline: 3.7873x; 1.0119x over previous
//
#include <hip/hip_runtime.h>
#include <stdint.h>

#define NPIX 4096
#define LOG2E 1.44269504088896340736f

typedef __bf16 bf16x8 __attribute__((ext_vector_type(8)));
typedef float  f32x4  __attribute__((ext_vector_type(4)));
typedef unsigned long long ull;

union FragU {
  bf16x8 f;
  uint4  u;
  ull    q[2];
  unsigned short s[8];
};

static __device__ __forceinline__ unsigned short f2bf(float x) {
  unsigned int u = __float_as_uint(x);
  u += 0x7FFFu + ((u >> 16) & 1u);
  return (unsigned short)(u >> 16);
}
static __device__ __forceinline__ float bf2f(unsigned short s) {
  return __uint_as_float(((unsigned int)s) << 16);
}
static __device__ __forceinline__ unsigned int pack2(unsigned short a, unsigned short b) {
  return (unsigned int)a | ((unsigned int)b << 16);
}
static __device__ __forceinline__ float e2(float x) { return __builtin_amdgcn_exp2f(x); }

// Global-memory fragment load (16x16x32 A/B layout: 8B at byteOff, 8B at +32).
// VERIFIED layout (rounds 1-2-5-6-7-8, absmax 0.5).
static __device__ __forceinline__ bf16x8 load_frag(const unsigned short* base, int byteOff) {
  const char* p = reinterpret_cast<const char*>(base) + byteOff;
  uint2 a = *reinterpret_cast<const uint2*>(p);
  uint2 b = *reinterpret_cast<const uint2*>(p + 32);
  FragU fu;
  fu.u = make_uint4(a.x, a.y, b.x, b.y);
  return fu.f;
}

// 8B-block swizzle: block beta (0..15 within a 128B row) stored at position
//   pi(row,beta) = ((beta + 2*(row&7)) & 15) ^ ((row>>3)&1)
// Per quarter-wave (16 lanes, rows f*16+lr): rotation spreads lr&7, the
// row-bit-3 XOR separates lr vs lr+8 -> 16 distinct 8B slots = all 32 banks
// exactly once (fixes round-8's residual 2-way conflict). Writes: 16B chunks
// stay 16-aligned; the XOR = swap of the two 8B halves, wave-uniform.
static __device__ __forceinline__ int pib(int row, int beta) {
  return ((beta + 2 * (row & 7)) & 15) ^ ((row >> 3) & 1);
}

// LDS fragment load from a 64x64-short tile, row-major 128B rows, swizzled.
static __device__ __forceinline__ bf16x8 lds_frag(const char* base, int row, int cb) {
  const int rb = row << 7;
  ull a = *reinterpret_cast<const ull*>(base + rb + (pib(row, cb >> 3) << 3));
  ull b = *reinterpret_cast<const ull*>(base + rb + (pib(row, (cb + 32) >> 3) << 3));
  FragU fu;
  fu.q[0] = a; fu.q[1] = b;
  return fu.f;
}

// Thread t stages linear tile bytes [t*16,+16) and [4096+t*16,+16), swizzled.
// 16B chunk covers blocks {e, e+1} (e even); when (row>>3)&1 the halves swap.
static __device__ __forceinline__ void stage_write(char* dst, int t, uint4 r0, uint4 r1) {
  const int o0 = t * 16, o1 = 4096 + t * 16;
  const int w0 = o0 >> 7, w1 = o1 >> 7;
  const int e0 = ((((o0 & 127) >> 3) + 2 * (w0 & 7)) & 15);
  const int e1 = ((((o1 & 127) >> 3) + 2 * (w1 & 7)) & 15);
  const uint4 a0 = ((w0 >> 3) & 1) ? make_uint4(r0.z, r0.w, r0.x, r0.y) : r0;
  const uint4 a1 = ((w1 >> 3) & 1) ? make_uint4(r1.z, r1.w, r1.x, r1.y) : r1;
  *reinterpret_cast<uint4*>(dst + (w0 << 7) + (e0 << 3)) = a0;
  *reinterpret_cast<uint4*>(dst + (w1 << 7) + (e1 << 3)) = a1;
}

// ---------------------------------------------------------------------------
// Kernel 1: q,k,v = 1x1 conv.  qT,kT stored (B,N,64) bf16; v stored (B,64,N).
// q scaled by LOG2E. VERBATIM round 8 (verified).
// ---------------------------------------------------------------------------
__global__ __launch_bounds__(256) void qkv_proj(
    const float* __restrict__ x,
    const float* __restrict__ Wq, const float* __restrict__ bq,
    const float* __restrict__ Wk, const float* __restrict__ bk,
    const float* __restrict__ Wv, const float* __restrict__ bv,
    unsigned short* __restrict__ qT, unsigned short* __restrict__ kT,
    unsigned short* __restrict__ vC)
{
  const int t  = threadIdx.x;
  const int b  = blockIdx.y;
  const int n  = blockIdx.x * 256 + t;
  const int o0 = blockIdx.z * 16;

  float xv[64];
  #pragma unroll
  for (int c = 0; c < 64; ++c) xv[c] = x[((size_t)b * 64 + c) * NPIX + n];

  const float* Wp[3] = {Wq, Wk, Wv};
  const float* Bp[3] = {bq, bk, bv};

  #pragma unroll
  for (int p = 0; p < 3; ++p) {
    const float* W  = Wp[p];
    const float* Bv = Bp[p];
    unsigned short outv[16];
    #pragma unroll
    for (int oo = 0; oo < 16; ++oo) {
      float acc = Bv[o0 + oo];
      #pragma unroll
      for (int c = 0; c < 64; ++c) acc += W[(o0 + oo) * 64 + c] * xv[c];
      if (p == 0) acc *= LOG2E;      // exp(q.k) == exp2((q*log2e).k)
      outv[oo] = f2bf(acc);
    }
    if (p < 2) {
      unsigned short* dst = (p == 0 ? qT : kT) + ((size_t)b * NPIX + n) * 64 + o0;
      uint4 w0 = make_uint4(pack2(outv[0], outv[1]),  pack2(outv[2], outv[3]),
                            pack2(outv[4], outv[5]),  pack2(outv[6], outv[7]));
      uint4 w1 = make_uint4(pack2(outv[8], outv[9]),  pack2(outv[10], outv[11]),
                            pack2(outv[12], outv[13]), pack2(outv[14], outv[15]));
      *reinterpret_cast<uint4*>(dst)     = w0;
      *reinterpret_cast<uint4*>(dst + 8) = w1;
    } else {
      #pragma unroll
      for (int oo = 0; oo < 16; ++oo)
        vC[((size_t)b * 64 + o0 + oo) * NPIX + n] = outv[oo];
    }
  }
}

// ---------------------------------------------------------------------------
// Kernel 2: Zpart[part][b][j] = sum over this part's i of 2^(q'_j . k_i).
// Round-8 structure; new conflict-free swizzle.
// ---------------------------------------------------------------------------
__global__ __launch_bounds__(256, 2) void attn_rowsum(
    const unsigned short* __restrict__ qT, const unsigned short* __restrict__ kT,
    float* __restrict__ Zpart, int ntiles)
{
  __shared__ __align__(16) char sK[2 * 8192];

  const int t    = threadIdx.x;
  const int b    = blockIdx.y;
  const int part = blockIdx.z;
  const int lane = t & 63;
  const int wv   = t >> 6;
  const int j0   = blockIdx.x * 256 + wv * 64;
  const int lr   = lane & 15;
  const int lg   = lane >> 4;

  bf16x8 aq0[4], aq1[4];
  #pragma unroll
  for (int f = 0; f < 4; ++f) {
    const unsigned short* qrow = qT + ((size_t)b * NPIX + j0 + f * 16 + lr) * 64;
    aq0[f] = load_frag(qrow, lg * 8);
    aq1[f] = load_frag(qrow, 64 + lg * 8);
  }

  const char* kbase = reinterpret_cast<const char*>(kT) + (size_t)b * NPIX * 128
                      + (size_t)part * ntiles * 8192;

  float zacc[4][4];
  #pragma unroll
  for (int f = 0; f < 4; ++f)
    #pragma unroll
    for (int r = 0; r < 4; ++r) zacc[f][r] = 0.f;

  uint4 r0 = *reinterpret_cast<const uint4*>(kbase + t * 16);
  uint4 r1 = *reinterpret_cast<const uint4*>(kbase + 4096 + t * 16);

  for (int tile = 0; tile < ntiles; ++tile) {
    char* buf = sK + (tile & 1) * 8192;
    stage_write(buf, t, r0, r1);
    __syncthreads();
    if (tile + 1 < ntiles) {
      const char* src = kbase + (size_t)(tile + 1) * 8192;
      r0 = *reinterpret_cast<const uint4*>(src + t * 16);
      r1 = *reinterpret_cast<const uint4*>(src + 4096 + t * 16);
    }
    bf16x8 kf0[4], kf1[4];
    #pragma unroll
    for (int s = 0; s < 4; ++s) {
      kf0[s] = lds_frag(buf, s * 16 + lr, lg * 8);
      kf1[s] = lds_frag(buf, s * 16 + lr, 64 + lg * 8);
    }
    #pragma unroll
    for (int f = 0; f < 4; ++f) {
      #pragma unroll
      for (int s = 0; s < 4; ++s) {
        f32x4 S = {0.f, 0.f, 0.f, 0.f};
        S = __builtin_amdgcn_mfma_f32_16x16x32_bf16(aq0[f], kf0[s], S, 0, 0, 0);
        S = __builtin_amdgcn_mfma_f32_16x16x32_bf16(aq1[f], kf1[s], S, 0, 0, 0);
        zacc[f][0] += e2(S[0]);
        zacc[f][1] += e2(S[1]);
        zacc[f][2] += e2(S[2]);
        zacc[f][3] += e2(S[3]);
      }
    }
    __syncthreads();
  }

  #pragma unroll
  for (int f = 0; f < 4; ++f) {
    #pragma unroll
    for (int m = 8; m >= 1; m >>= 1) {
      #pragma unroll
      for (int r = 0; r < 4; ++r) zacc[f][r] += __shfl_xor(zacc[f][r], m, 64);
    }
  }
  if (lr == 0) {
    float* dst = Zpart + ((size_t)part * 8 + b) * NPIX + j0 + lg * 4;
    #pragma unroll
    for (int f = 0; f < 4; ++f) {
      #pragma unroll
      for (int r = 0; r < 4; ++r) dst[f * 16 + r] = zacc[f][r];
    }
  }
}

// ---------------------------------------------------------------------------
// Kernel 2.5 (fused zred+vscale): v'[c,n] = v[c,n] / sum_p Zpart[p][b][n].
// VERBATIM rounds 6-8 (verified).
// ---------------------------------------------------------------------------
__global__ __launch_bounds__(256) void vscale(
    unsigned short* __restrict__ vC, const float* __restrict__ Zpart, int nparts)
{
  const int idx = blockIdx.x * 256 + threadIdx.x;   // 0..262143
  const int jc  = idx & 511;
  const int b   = idx >> 15;
  unsigned short* p = vC + (size_t)idx * 8;
  const float* zb = Zpart + (size_t)b * NPIX + jc * 8;
  float z[8];
  #pragma unroll
  for (int e = 0; e < 8; ++e) z[e] = 0.f;
  for (int pp = 0; pp < nparts; ++pp) {
    const float* zp = zb + (size_t)pp * 8 * NPIX;
    #pragma unroll
    for (int e = 0; e < 8; ++e) z[e] += zp[e];
  }
  FragU v;
  v.q[0] = reinterpret_cast<const ull*>(p)[0];
  v.q[1] = reinterpret_cast<const ull*>(p)[1];
  #pragma unroll
  for (int e = 0; e < 8; ++e) v.s[e] = f2bf(bf2f(v.s[e]) * (1.0f / z[e]));
  reinterpret_cast<ull*>(p)[0] = v.q[0];
  reinterpret_cast<ull*>(p)[1] = v.q[1];
}

// ---------------------------------------------------------------------------
// Kernel 3: resP[part][b][c][i] = sum over part's j of 2^(q'_j.k_i)*v'[c,j].
// Round-8 structure; new conflict-free swizzle; resP now bf16 (halves the
// dominant HBM write stream 64->32 MB).
// ---------------------------------------------------------------------------
__global__ __launch_bounds__(256, 2) void attn_pv(
    const unsigned short* __restrict__ qT, const unsigned short* __restrict__ kT,
    const unsigned short* __restrict__ vC, unsigned short* __restrict__ resP,
    int ntiles)
{
  __shared__ __align__(16) char sQ[2 * 8192];
  __shared__ __align__(16) char sV[2 * 8192];

  const int t    = threadIdx.x;
  const int b    = blockIdx.y;
  const int part = blockIdx.z;
  const int lane = t & 63;
  const int wv   = t >> 6;
  const int i0   = blockIdx.x * 256 + wv * 64;
  const int lr   = lane & 15;
  const int lg   = lane >> 4;
  const int jstart = part * ntiles * 64;

  bf16x8 kf0[4], kf1[4];
  #pragma unroll
  for (int s = 0; s < 4; ++s) {
    const unsigned short* krow = kT + ((size_t)b * NPIX + i0 + s * 16 + lr) * 64;
    kf0[s] = load_frag(krow, lg * 8);
    kf1[s] = load_frag(krow, 64 + lg * 8);
  }

  const char* qbase = reinterpret_cast<const char*>(qT) + ((size_t)b * NPIX + jstart) * 128;
  const char* vbase = reinterpret_cast<const char*>(vC) + (size_t)b * 64 * 8192
                      + (size_t)jstart * 2;

  const int vo0_row = (t * 16) >> 7,        vo0_col = (t * 16) & 127;
  const int vo1_row = (4096 + t * 16) >> 7, vo1_col = (4096 + t * 16) & 127;

  f32x4 acc[4][4];
  #pragma unroll
  for (int m = 0; m < 4; ++m)
    #pragma unroll
    for (int s = 0; s < 4; ++s) acc[m][s] = (f32x4){0.f, 0.f, 0.f, 0.f};

  uint4 q0 = *reinterpret_cast<const uint4*>(qbase + t * 16);
  uint4 q1 = *reinterpret_cast<const uint4*>(qbase + 4096 + t * 16);
  uint4 v0 = *reinterpret_cast<const uint4*>(vbase + (size_t)vo0_row * 8192 + vo0_col);
  uint4 v1 = *reinterpret_cast<const uint4*>(vbase + (size_t)vo1_row * 8192 + vo1_col);

  for (int tile = 0; tile < ntiles; ++tile) {
    char* Qt = sQ + (tile & 1) * 8192;
    char* Vt = sV + (tile & 1) * 8192;
    stage_write(Qt, t, q0, q1);
    stage_write(Vt, t, v0, v1);
    __syncthreads();
    if (tile + 1 < ntiles) {
      const char* qsrc = qbase + (size_t)(tile + 1) * 8192;
      q0 = *reinterpret_cast<const uint4*>(qsrc + t * 16);
      q1 = *reinterpret_cast<const uint4*>(qsrc + 4096 + t * 16);
      const int jb = (tile + 1) * 128;
      v0 = *reinterpret_cast<const uint4*>(vbase + (size_t)vo0_row * 8192 + jb + vo0_col);
      v1 = *reinterpret_cast<const uint4*>(vbase + (size_t)vo1_row * 8192 + jb + vo1_col);
    }

    bf16x8 qf0[4], qf1[4], vf0[4], vf1[4];
    #pragma unroll
    for (int f = 0; f < 4; ++f) {
      qf0[f] = lds_frag(Qt, f * 16 + lr, lg * 8);
      qf1[f] = lds_frag(Qt, f * 16 + lr, 64 + lg * 8);
    }
    #pragma unroll
    for (int m = 0; m < 4; ++m) {
      vf0[m] = lds_frag(Vt, m * 16 + lr, lg * 8);
      vf1[m] = lds_frag(Vt, m * 16 + lr, 64 + lg * 8);
    }

    #pragma unroll
    for (int s = 0; s < 4; ++s) {
      f32x4 sj[4];
      #pragma unroll
      for (int f = 0; f < 4; ++f) {
        sj[f] = (f32x4){0.f, 0.f, 0.f, 0.f};
        sj[f] = __builtin_amdgcn_mfma_f32_16x16x32_bf16(qf0[f], kf0[s], sj[f], 0, 0, 0);
        sj[f] = __builtin_amdgcn_mfma_f32_16x16x32_bf16(qf1[f], kf1[s], sj[f], 0, 0, 0);
      }
      FragU pe0, pe1;
      #pragma unroll
      for (int r = 0; r < 4; ++r) {
        pe0.f[r]     = (__bf16)e2(sj[0][r]);
        pe0.f[4 + r] = (__bf16)e2(sj[1][r]);
        pe1.f[r]     = (__bf16)e2(sj[2][r]);
        pe1.f[4 + r] = (__bf16)e2(sj[3][r]);
      }
      #pragma unroll
      for (int m = 0; m < 4; ++m) {
        acc[m][s] = __builtin_amdgcn_mfma_f32_16x16x32_bf16(vf0[m], pe0.f, acc[m][s], 0, 0, 0);
        acc[m][s] = __builtin_amdgcn_mfma_f32_16x16x32_bf16(vf1[m], pe1.f, acc[m][s], 0, 0, 0);
      }
    }
    __syncthreads();
  }

  unsigned short* rbase = resP + ((size_t)part * 8 + b) * 64 * NPIX;
  #pragma unroll
  for (int m = 0; m < 4; ++m) {
    #pragma unroll
    for (int s = 0; s < 4; ++s) {
      #pragma unroll
      for (int r = 0; r < 4; ++r) {
        rbase[(size_t)(m * 16 + lg * 4 + r) * NPIX + i0 + s * 16 + lr] = f2bf(acc[m][s][r]);
      }
    }
  }
}

// ---------------------------------------------------------------------------
// Kernel 3.5: res = sum_p resP (bf16 partials -> fp32).  262144 threads,
// 8 elements each (one uint4 per part, coalesced).
// ---------------------------------------------------------------------------
__global__ __launch_bounds__(256) void resred(
    const unsigned short* __restrict__ resP, float* __restrict__ res, int nparts)
{
  const size_t idx = (size_t)blockIdx.x * 256 + threadIdx.x;   // uint4 chunk
  const uint4* src = reinterpret_cast<const uint4*>(resP) + idx;
  float a[8];
  #pragma unroll
  for (int e = 0; e < 8; ++e) a[e] = 0.f;
  for (int p = 0; p < nparts; ++p) {
    FragU u;
    u.u = src[(size_t)p * 262144];
    #pragma unroll
    for (int e = 0; e < 8; ++e) a[e] += bf2f(u.s[e]);
  }
  float4 o0 = make_float4(a[0], a[1], a[2], a[3]);
  float4 o1 = make_float4(a[4], a[5], a[6], a[7]);
  reinterpret_cast<float4*>(res)[idx * 2]     = o0;
  reinterpret_cast<float4*>(res)[idx * 2 + 1] = o1;
}

// ---------------------------------------------------------------------------
// Kernel 4: out = Wo*res + bo + res.  VERBATIM rounds 6-8 (verified).
// ---------------------------------------------------------------------------
__global__ __launch_bounds__(256) void out_proj(
    const float* __restrict__ res, const float* __restrict__ Wo,
    const float* __restrict__ bo, float* __restrict__ out)
{
  const int t  = threadIdx.x;
  const int b  = blockIdx.y;
  const int n  = blockIdx.x * 256 + t;
  const int o0 = blockIdx.z * 16;

  float rv[64];
  #pragma unroll
  for (int c = 0; c < 64; ++c) rv[c] = res[((size_t)b * 64 + c) * NPIX + n];

  #pragma unroll
  for (int oo = 0; oo < 16; ++oo) {
    float acc = bo[o0 + oo];
    #pragma unroll
    for (int c = 0; c < 64; ++c) acc += Wo[(o0 + oo) * 64 + c] * rv[c];
    acc += res[((size_t)b * 64 + o0 + oo) * NPIX + n];
    out[((size_t)b * 64 + o0 + oo) * NPIX + n] = acc;
  }
}

// ---------------------------------------------------------------------------
extern "C" void kernel_launch(void* const* d_in, const int* in_sizes, int n_in,
                              void* d_out, int out_size, void* d_ws, size_t ws_size,
                              hipStream_t stream) {
  const float* x  = (const float*)d_in[0];
  const float* Wq = (const float*)d_in[1];
  const float* bq = (const float*)d_in[2];
  const float* Wk = (const float*)d_in[3];
  const float* bk = (const float*)d_in[4];
  const float* Wv = (const float*)d_in[5];
  const float* bv = (const float*)d_in[6];
  const float* Wo = (const float*)d_in[7];
  const float* bo = (const float*)d_in[8];
  float* out = (float*)d_out;

  char* ws = (char*)d_ws;
  // res (8 MB) aliases qT+kT: written by resred only after attn_pv is done
  // with qT/kT/vC, and read only by out_proj.
  unsigned short* qT   = (unsigned short*)(ws);                          // 4 MB
  unsigned short* kT   = (unsigned short*)(ws + ((size_t)4 << 20));      // 4 MB
  float* res           = (float*)(ws);                                   // 8 MB (alias)
  unsigned short* vC   = (unsigned short*)(ws + ((size_t)8 << 20));      // 4 MB
  float* Zpart         = (float*)(ws + ((size_t)12 << 20));              // <=1 MB
  unsigned short* resP = (unsigned short*)(ws + ((size_t)13 << 20));     // nparts*4 MB

  int nparts;
  const size_t MB = (size_t)1 << 20;
  if      (ws_size >= 13 * MB + 8 * 4 * MB) nparts = 8;   // grid 1024 -> 4 blocks/CU
  else if (ws_size >= 13 * MB + 4 * 4 * MB) nparts = 4;
  else if (ws_size >= 13 * MB + 2 * 4 * MB) nparts = 2;
  else                                      nparts = 1;
  const int ntiles = 64 / nparts;

  qkv_proj<<<dim3(16, 8, 4), 256, 0, stream>>>(x, Wq, bq, Wk, bk, Wv, bv, qT, kT, vC);
  attn_rowsum<<<dim3(16, 8, nparts), 256, 0, stream>>>(qT, kT, Zpart, ntiles);
  vscale<<<dim3(1024), 256, 0, stream>>>(vC, Zpart, nparts);
  attn_pv<<<dim3(16, 8, nparts), 256, 0, stream>>>(qT, kT, vC, resP, ntiles);
  resred<<<dim3(1024), 256, 0, stream>>>(resP, res, nparts);
  out_proj<<<dim3(16, 8, 4), 256, 0, stream>>>(res, Wo, bo, out);
}